// Round 1
// baseline (1472.977 us; speedup 1.0000x reference)
//
#include <hip/hip_runtime.h>
#include <hip/hip_bf16.h>
#include <math.h>

typedef __attribute__((ext_vector_type(8))) short s16x8;
typedef __attribute__((ext_vector_type(4))) short s16x4;
typedef __attribute__((ext_vector_type(4))) float f32x4;
typedef __attribute__((ext_vector_type(8))) __bf16 bf16x8;

#define MFMA16(a, b, c) __builtin_amdgcn_mfma_f32_16x16x32_bf16( \
    __builtin_bit_cast(bf16x8, (a)), __builtin_bit_cast(bf16x8, (b)), (c), 0, 0, 0)

__device__ __forceinline__ short f2b(float f) {
    union { float f; unsigned u; } x; x.f = f;
    unsigned u = x.u;
    unsigned r = (u + 0x7FFFu + ((u >> 16) & 1u)) >> 16;
    return (short)r;
}
__device__ __forceinline__ float b2f(short b) {
    union { unsigned u; float f; } x;
    x.u = ((unsigned)(unsigned short)b) << 16;
    return x.f;
}

// ---------------- fp32 -> bf16 convert (vectorized, grid-stride) ----------------
__global__ void k_f32_to_bf16(const float* __restrict__ in, short* __restrict__ out, long n) {
    long i = ((long)blockIdx.x * blockDim.x + threadIdx.x) * 4;
    long stride = (long)gridDim.x * blockDim.x * 4;
    for (; i < n; i += stride) {
        float4 v = *(const float4*)(in + i);
        s16x4 o = { f2b(v.x), f2b(v.y), f2b(v.z), f2b(v.w) };
        *(s16x4*)(out + i) = o;
    }
}

// ---------------- log(size) with -inf-ish padding ----------------
__global__ void k_logsize(const float* __restrict__ size, float* __restrict__ out,
                          int B, int T, int SP) {
    int i = blockIdx.x * blockDim.x + threadIdx.x;
    if (i >= B * SP) return;
    int b = i / SP, s = i % SP;
    out[i] = (s < T) ? logf(size[b * T + s]) : -1e30f;
}

// ---------------- generic bf16 GEMM: C = (A @ B^T + bias) * alpha ----------------
// A: [M][K] bf16, Bm: [N][K] bf16 (nn.Linear weight layout), batched via blockIdx.z.
__global__ __launch_bounds__(256) void k_gemm_bt(
    const short* __restrict__ A, const short* __restrict__ Bm,
    const float* __restrict__ bias, float alpha,
    short* __restrict__ Cb, float* __restrict__ Cf,
    int M, int N, int K, int ldc,
    long sA, long sB, long sC) {
    int bz = blockIdx.z;
    const short* Ab = A + (long)bz * sA;
    const short* Bb = Bm + (long)bz * sB;
    int row0 = blockIdx.y * 128, col0 = blockIdx.x * 128;
    __shared__ short As[128][40];
    __shared__ short Bs[128][40];
    int tid = threadIdx.x;
    int lane = tid & 63, wid = tid >> 6;
    int wr = wid >> 1, wc = wid & 1;
    int lr = lane & 15, lk = (lane >> 4) * 8;
    f32x4 acc[4][4];
    for (int i = 0; i < 4; i++)
        for (int j = 0; j < 4; j++)
            for (int q = 0; q < 4; q++) acc[i][j][q] = 0.f;
    for (int k0 = 0; k0 < K; k0 += 32) {
        __syncthreads();
        for (int c = tid; c < 512; c += 256) {
            int r = c >> 2, kk = (c & 3) * 8;
            int ga = row0 + r;
            s16x8 va = {0,0,0,0,0,0,0,0};
            if (ga < M) va = *(const s16x8*)(Ab + (long)ga * K + k0 + kk);
            *(s16x8*)(&As[r][kk]) = va;
            int gb = col0 + r;
            s16x8 vb = {0,0,0,0,0,0,0,0};
            if (gb < N) vb = *(const s16x8*)(Bb + (long)gb * K + k0 + kk);
            *(s16x8*)(&Bs[r][kk]) = vb;
        }
        __syncthreads();
        s16x8 af[4], bfr[4];
        for (int i = 0; i < 4; i++) af[i] = *(const s16x8*)(&As[wr * 64 + i * 16 + lr][lk]);
        for (int j = 0; j < 4; j++) bfr[j] = *(const s16x8*)(&Bs[wc * 64 + j * 16 + lr][lk]);
        for (int i = 0; i < 4; i++)
            for (int j = 0; j < 4; j++)
                acc[i][j] = MFMA16(af[i], bfr[j], acc[i][j]);
    }
    for (int i = 0; i < 4; i++) {
        int rbase = row0 + wr * 64 + i * 16 + (lane >> 4) * 4;
        for (int j = 0; j < 4; j++) {
            int c = col0 + wc * 64 + j * 16 + lr;
            if (c >= N) continue;
            float bv = bias ? bias[c] : 0.f;
            for (int q = 0; q < 4; q++) {
                int r = rbase + q;
                if (r >= M) continue;
                float y = (acc[i][j][q] + bv) * alpha;
                long off = sC * bz + (long)r * ldc + c;
                if (Cb) Cb[off] = f2b(y);
                else    Cf[off] = y;
            }
        }
    }
}

// ---------------- mean over heads of K: [B,T,D] ----------------
__global__ void k_mean_keys(const short* __restrict__ Kb, float* __restrict__ out,
                            int B, int T, int D, int H) {
    int i = blockIdx.x * blockDim.x + threadIdx.x;
    int n = B * T * D;
    if (i >= n) return;
    int d = i % D;
    int bt = i / D;
    const short* p = Kb + (long)bt * (D * H) + d;
    float s = 0.f;
    for (int h = 0; h < H; ++h) s += b2f(p[h * D]);
    out[i] = s * (1.0f / H);
}

// ---------------- reduce att_score partials over batch ----------------
__global__ void k_att_reduce(const float* __restrict__ part, float* __restrict__ out,
                             int n, int nb, long stride) {
    int i = blockIdx.x * blockDim.x + threadIdx.x;
    if (i >= n) return;
    float s = 0.f;
    for (int b = 0; b < nb; ++b) s += part[(long)b * stride + i];
    out[i] = s * (1.0f / 256.0f);
}

// ---------------- flash attention with log-size key bias ----------------
// grid: (ceil(T/64), H, B), block 256 (4 waves x 16 q-rows)
__global__ __launch_bounds__(256) void k_flash(
    const short* __restrict__ Q, const short* __restrict__ Kb, const short* __restrict__ Vb,
    const float* __restrict__ logsz, short* __restrict__ Ctx,
    int B, int T, int E, int H, int SP) {
    int b = blockIdx.z, h = blockIdx.y, t0 = blockIdx.x * 64;
    __shared__ short Qs[64][72];
    __shared__ short Ks[64][72];
    __shared__ short Vt[64][72];   // transposed: Vt[d][s]
    __shared__ short Ps[4][16][72];
    __shared__ float Ls[64];
    int tid = threadIdx.x, wid = tid >> 6, lane = tid & 63;
    int lr = lane & 15, lg = lane >> 4;
    const short* qb = Q + ((long)b * T + t0) * E + h * 64;
    for (int c = tid; c < 512; c += 256) {
        int r = c >> 3, d0 = (c & 7) * 8;
        s16x8 v = {0,0,0,0,0,0,0,0};
        if (t0 + r < T) v = *(const s16x8*)(qb + (long)r * E + d0);
        *(s16x8*)(&Qs[r][d0]) = v;
    }
    float m[4], l[4];
    f32x4 o[4];
    for (int q = 0; q < 4; q++) { m[q] = -INFINITY; l[q] = 0.f; }
    for (int jd = 0; jd < 4; jd++)
        for (int q = 0; q < 4; q++) o[jd][q] = 0.f;
    const short* kb = Kb + (long)b * T * E + h * 64;
    const short* vb = Vb + (long)b * T * E + h * 64;
    for (int s0 = 0; s0 < T; s0 += 64) {
        __syncthreads();
        for (int c = tid; c < 512; c += 256) {
            int r = c >> 3, d0 = (c & 7) * 8;
            s16x8 kv = {0,0,0,0,0,0,0,0}, vv = {0,0,0,0,0,0,0,0};
            if (s0 + r < T) {
                kv = *(const s16x8*)(kb + (long)(s0 + r) * E + d0);
                vv = *(const s16x8*)(vb + (long)(s0 + r) * E + d0);
            }
            *(s16x8*)(&Ks[r][d0]) = kv;
            for (int j = 0; j < 8; j++) Vt[d0 + j][r] = vv[j];
        }
        if (tid < 64) Ls[tid] = logsz[b * SP + s0 + tid];
        __syncthreads();
        f32x4 sf[4];
        for (int j = 0; j < 4; j++)
            for (int q = 0; q < 4; q++) sf[j][q] = 0.f;
        for (int ks = 0; ks < 2; ++ks) {
            s16x8 aq = *(const s16x8*)(&Qs[wid * 16 + lr][ks * 32 + lg * 8]);
            for (int j = 0; j < 4; j++) {
                s16x8 bk = *(const s16x8*)(&Ks[j * 16 + lr][ks * 32 + lg * 8]);
                sf[j] = MFMA16(aq, bk, sf[j]);
            }
        }
        float tmax[4];
        for (int q = 0; q < 4; q++) tmax[q] = -INFINITY;
        for (int j = 0; j < 4; j++) {
            float bl = Ls[j * 16 + lr];
            for (int q = 0; q < 4; q++) {
                sf[j][q] += bl;
                tmax[q] = fmaxf(tmax[q], sf[j][q]);
            }
        }
        for (int q = 0; q < 4; q++)
            for (int msk = 1; msk < 16; msk <<= 1)
                tmax[q] = fmaxf(tmax[q], __shfl_xor(tmax[q], msk));
        float al[4], rs[4];
        for (int q = 0; q < 4; q++) {
            float mn = fmaxf(m[q], tmax[q]);
            al[q] = __expf(m[q] - mn);
            m[q] = mn;
            rs[q] = 0.f;
        }
        for (int j = 0; j < 4; j++)
            for (int q = 0; q < 4; q++) {
                float p = __expf(sf[j][q] - m[q]);
                sf[j][q] = p;
                rs[q] += p;
            }
        for (int q = 0; q < 4; q++) {
            for (int msk = 1; msk < 16; msk <<= 1) rs[q] += __shfl_xor(rs[q], msk);
            l[q] = l[q] * al[q] + rs[q];
        }
        for (int jd = 0; jd < 4; jd++)
            for (int q = 0; q < 4; q++) o[jd][q] *= al[q];
        for (int j = 0; j < 4; j++)
            for (int q = 0; q < 4; q++)
                Ps[wid][lg * 4 + q][j * 16 + lr] = f2b(sf[j][q]);
        __syncthreads();
        for (int ks = 0; ks < 2; ++ks) {
            s16x8 ap = *(const s16x8*)(&Ps[wid][lr][ks * 32 + lg * 8]);
            for (int jd = 0; jd < 4; jd++) {
                s16x8 bv = *(const s16x8*)(&Vt[jd * 16 + lr][ks * 32 + lg * 8]);
                o[jd] = MFMA16(ap, bv, o[jd]);
            }
        }
    }
    short* cb = Ctx + ((long)b * T + t0) * E + h * 64;
    for (int q = 0; q < 4; q++) {
        int t = wid * 16 + lg * 4 + q;
        if (t0 + t >= T) continue;
        float inv = 1.f / l[q];
        for (int jd = 0; jd < 4; jd++)
            cb[(long)t * E + jd * 16 + lr] = f2b(o[jd][q] * inv);
    }
}

extern "C" void kernel_launch(void* const* d_in, const int* in_sizes, int n_in,
                              void* d_out, int out_size, void* d_ws, size_t ws_size,
                              hipStream_t stream) {
    (void)in_sizes; (void)n_in; (void)out_size; (void)ws_size;
    const int B = 16, T = 577, E = 1024, H = 16, D = 64;
    const int SP = 640;
    const float* hs   = (const float*)d_in[0];
    const float* size = (const float*)d_in[1];
    const float* wq   = (const float*)d_in[2];
    const float* bq   = (const float*)d_in[3];
    const float* wk   = (const float*)d_in[4];
    const float* bk   = (const float*)d_in[5];
    const float* wv   = (const float*)d_in[6];
    const float* bv   = (const float*)d_in[7];
    const float* wo   = (const float*)d_in[8];
    const float* bo   = (const float*)d_in[9];

    float* out_attn = (float*)d_out;                  // B*T*E
    float* out_mk   = out_attn + (long)B * T * E;     // B*T*D
    float* out_as   = out_mk + (long)B * T * D;       // T*T

    long nBTE = (long)B * T * E;
    long nEE  = (long)E * E;
    char* ws = (char*)d_ws;
    short* hs_b  = (short*)ws; ws += nBTE * 2;
    short* wq_b  = (short*)ws; ws += nEE * 2;
    short* wk_b  = (short*)ws; ws += nEE * 2;
    short* wv_b  = (short*)ws; ws += nEE * 2;
    short* wo_b  = (short*)ws; ws += nEE * 2;
    short* q_b   = (short*)ws; ws += nBTE * 2;
    short* k_b   = (short*)ws; ws += nBTE * 2;
    short* v_b   = (short*)ws; ws += nBTE * 2;
    short* ctx_b = (short*)ws; ws += nBTE * 2;
    float* logsz = (float*)ws; ws += (long)B * SP * 4;
    float* att_p = (float*)ws; ws += (long)B * T * T * 4;

    // converts
    k_f32_to_bf16<<<2048, 256, 0, stream>>>(hs, hs_b, nBTE);
    k_f32_to_bf16<<<1024, 256, 0, stream>>>(wq, wq_b, nEE);
    k_f32_to_bf16<<<1024, 256, 0, stream>>>(wk, wk_b, nEE);
    k_f32_to_bf16<<<1024, 256, 0, stream>>>(wv, wv_b, nEE);
    k_f32_to_bf16<<<1024, 256, 0, stream>>>(wo, wo_b, nEE);
    k_logsize<<<(B * SP + 255) / 256, 256, 0, stream>>>(size, logsz, B, T, SP);

    dim3 blk(256);
    // QKV projections: M = B*T, N = K = E
    dim3 g_qkv(E / 128, (B * T + 127) / 128, 1);
    k_gemm_bt<<<g_qkv, blk, 0, stream>>>(hs_b, wq_b, bq, 0.125f, q_b, nullptr,
                                         B * T, E, E, E, 0, 0, 0);
    k_gemm_bt<<<g_qkv, blk, 0, stream>>>(hs_b, wk_b, bk, 1.0f, k_b, nullptr,
                                         B * T, E, E, E, 0, 0, 0);
    k_gemm_bt<<<g_qkv, blk, 0, stream>>>(hs_b, wv_b, bv, 1.0f, v_b, nullptr,
                                         B * T, E, E, E, 0, 0, 0);

    // att_score partials: per-batch q @ k^T over full E, then reduce
    dim3 g_att((T + 127) / 128, (T + 127) / 128, B);
    k_gemm_bt<<<g_att, blk, 0, stream>>>(q_b, k_b, nullptr, 1.0f, nullptr, att_p,
                                         T, T, E, T, (long)T * E, (long)T * E, (long)T * T);
    k_att_reduce<<<((T * T) + 255) / 256, 256, 0, stream>>>(att_p, out_as, T * T, B, (long)T * T);

    // mean over heads of K
    k_mean_keys<<<((B * T * D) + 255) / 256, 256, 0, stream>>>(k_b, out_mk, B, T, D, H);

    // flash attention -> context (bf16)
    dim3 g_fl((T + 63) / 64, H, B);
    k_flash<<<g_fl, blk, 0, stream>>>(q_b, k_b, v_b, logsz, ctx_b, B, T, E, H, SP);

    // output projection -> fp32 d_out
    k_gemm_bt<<<g_qkv, blk, 0, stream>>>(ctx_b, wo_b, bo, 1.0f, nullptr, out_attn,
                                         B * T, E, E, E, 0, 0, 0);
}

// Round 2
// 388.525 us; speedup vs baseline: 3.7912x; 3.7912x over previous
//
#include <hip/hip_runtime.h>
#include <hip/hip_bf16.h>
#include <math.h>

typedef __attribute__((ext_vector_type(8))) short s16x8;
typedef __attribute__((ext_vector_type(4))) short s16x4;
typedef __attribute__((ext_vector_type(4))) float f32x4;
typedef __attribute__((ext_vector_type(8))) __bf16 bf16x8;

#define MFMA16(a, b, c) __builtin_amdgcn_mfma_f32_16x16x32_bf16( \
    __builtin_bit_cast(bf16x8, (a)), __builtin_bit_cast(bf16x8, (b)), (c), 0, 0, 0)

__device__ __forceinline__ short f2b(float f) {
    union { float f; unsigned u; } x; x.f = f;
    unsigned u = x.u;
    unsigned r = (u + 0x7FFFu + ((u >> 16) & 1u)) >> 16;
    return (short)r;
}
__device__ __forceinline__ float b2f(short b) {
    union { unsigned u; float f; } x;
    x.u = ((unsigned)(unsigned short)b) << 16;
    return x.f;
}

__device__ __forceinline__ void gload16(const void* g, void* l) {
    __builtin_amdgcn_global_load_lds(
        (const __attribute__((address_space(1))) unsigned int*)g,
        (__attribute__((address_space(3))) unsigned int*)l, 16, 0, 0);
}

// ---------------- fp32 -> bf16 convert (vectorized, grid-stride) ----------------
__global__ void k_f32_to_bf16(const float* __restrict__ in, short* __restrict__ out, long n) {
    long i = ((long)blockIdx.x * blockDim.x + threadIdx.x) * 4;
    long stride = (long)gridDim.x * blockDim.x * 4;
    for (; i < n; i += stride) {
        float4 v = *(const float4*)(in + i);
        s16x4 o = { f2b(v.x), f2b(v.y), f2b(v.z), f2b(v.w) };
        *(s16x4*)(out + i) = o;
    }
}

// ---------------- log(size) with -inf-ish padding ----------------
__global__ void k_logsize(const float* __restrict__ size, float* __restrict__ out,
                          int B, int T, int SP) {
    int i = blockIdx.x * blockDim.x + threadIdx.x;
    if (i >= B * SP) return;
    int b = i / SP, s = i % SP;
    out[i] = (s < T) ? logf(size[b * T + s]) : -1e30f;
}

// ---------------- m97-style GEMM core: C = (A @ B^T + bias) * alpha ----------------
// 128x128 tile, BK=64, linear LDS, global_load_lds width-16 staging.
// A: [M][K] bf16, Bm: [N][K] bf16. Edge tiles: clamp staging addr, mask epilogue.
__device__ __forceinline__ void gemm_core(
    const short* __restrict__ Ab, const short* __restrict__ Bb,
    const float* __restrict__ bias, float alpha,
    short* __restrict__ Cb, float* __restrict__ Cf,
    int M, int N, int K, int ldc, int row0, int col0) {
    __shared__ short As[128 * 64];
    __shared__ short Bs[128 * 64];
    int tid = threadIdx.x;
    int lane = tid & 63, wave = tid >> 6;
    int wr = wave >> 1, wc = wave & 1;
    int lr = lane & 15, lg = lane >> 4;
    f32x4 acc[4][4];
    #pragma unroll
    for (int i = 0; i < 4; i++)
        #pragma unroll
        for (int j = 0; j < 4; j++)
            #pragma unroll
            for (int q = 0; q < 4; q++) acc[i][j][q] = 0.f;

    for (int k0 = 0; k0 < K; k0 += 64) {
        __syncthreads();
        // stage A and B tiles: 1024 chunks of 16B each, 4 issues per thread per tile
        #pragma unroll
        for (int i = 0; i < 4; ++i) {
            int cw = i * 256 + wave * 64;          // wave-uniform chunk base
            int c = cw + lane;                      // this lane's chunk
            int r = c >> 3;                         // row in tile
            int cs = (c & 7) * 8;                   // short offset in row
            int ra = row0 + r; ra = ra < M ? ra : M - 1;
            gload16(Ab + (long)ra * K + k0 + cs, &As[cw * 8]);
            int rb = col0 + r; rb = rb < N ? rb : N - 1;
            gload16(Bb + (long)rb * K + k0 + cs, &Bs[cw * 8]);
        }
        __syncthreads();   // compiler drains vmcnt(0) before s_barrier
        #pragma unroll
        for (int ks = 0; ks < 2; ++ks) {
            s16x8 af[4], bfr[4];
            #pragma unroll
            for (int i = 0; i < 4; ++i)
                af[i] = *(const s16x8*)&As[(wr * 64 + i * 16 + lr) * 64 + ks * 32 + lg * 8];
            #pragma unroll
            for (int j = 0; j < 4; ++j)
                bfr[j] = *(const s16x8*)&Bs[(wc * 64 + j * 16 + lr) * 64 + ks * 32 + lg * 8];
            #pragma unroll
            for (int i = 0; i < 4; ++i)
                #pragma unroll
                for (int j = 0; j < 4; ++j)
                    acc[i][j] = MFMA16(af[i], bfr[j], acc[i][j]);
        }
    }
    #pragma unroll
    for (int i = 0; i < 4; i++) {
        int rbase = row0 + wr * 64 + i * 16 + lg * 4;
        #pragma unroll
        for (int j = 0; j < 4; j++) {
            int c = col0 + wc * 64 + j * 16 + lr;
            if (c >= N) continue;
            float bv = bias ? bias[c] : 0.f;
            #pragma unroll
            for (int q = 0; q < 4; q++) {
                int r = rbase + q;
                if (r >= M) continue;
                float y = (acc[i][j][q] + bv) * alpha;
                long off = (long)r * ldc + c;
                if (Cb) Cb[off] = f2b(y);
                else    Cf[off] = y;
            }
        }
    }
}

// fused QKV: z selects weight/bias/alpha/output
__global__ __launch_bounds__(256) void k_qkv(
    const short* __restrict__ hs,
    const short* __restrict__ wq, const short* __restrict__ wk, const short* __restrict__ wv,
    const float* __restrict__ bq, const float* __restrict__ bk, const float* __restrict__ bv,
    short* __restrict__ q, short* __restrict__ k, short* __restrict__ v,
    int M, int E) {
    int z = blockIdx.z;
    const short* W = (z == 0) ? wq : (z == 1) ? wk : wv;
    const float* bi = (z == 0) ? bq : (z == 1) ? bk : bv;
    short* C = (z == 0) ? q : (z == 1) ? k : v;
    float alpha = (z == 0) ? 0.125f : 1.0f;
    gemm_core(hs, W, bi, alpha, C, nullptr, M, E, E, E,
              blockIdx.y * 128, blockIdx.x * 128);
}

// att_score partials: per-batch q @ k^T (full E), fp32 out
__global__ __launch_bounds__(256) void k_att(
    const short* __restrict__ q, const short* __restrict__ k,
    float* __restrict__ attp, int T, int E) {
    int z = blockIdx.z;
    gemm_core(q + (long)z * T * E, k + (long)z * T * E, nullptr, 1.0f,
              nullptr, attp + (long)z * T * T, T, T, E, T,
              blockIdx.y * 128, blockIdx.x * 128);
}

// output projection: fp32 out
__global__ __launch_bounds__(256) void k_proj(
    const short* __restrict__ ctx, const short* __restrict__ wo,
    const float* __restrict__ bo, float* __restrict__ out, int M, int E) {
    gemm_core(ctx, wo, bo, 1.0f, nullptr, out, M, E, E, E,
              blockIdx.y * 128, blockIdx.x * 128);
}

// ---------------- mean over heads of K (vectorized): [B,T,D] ----------------
__global__ void k_mean_keys8(const short* __restrict__ Kb, float* __restrict__ out, int BT) {
    int i = blockIdx.x * blockDim.x + threadIdx.x;
    if (i >= BT * 8) return;
    int bt = i >> 3, d0 = (i & 7) * 8;
    const short* p = Kb + (long)bt * 1024 + d0;
    float s[8] = {0.f, 0.f, 0.f, 0.f, 0.f, 0.f, 0.f, 0.f};
    #pragma unroll
    for (int h = 0; h < 16; ++h) {
        s16x8 v = *(const s16x8*)(p + h * 64);
        #pragma unroll
        for (int j = 0; j < 8; ++j) s[j] += b2f(v[j]);
    }
    float4 o0 = {s[0] * 0.0625f, s[1] * 0.0625f, s[2] * 0.0625f, s[3] * 0.0625f};
    float4 o1 = {s[4] * 0.0625f, s[5] * 0.0625f, s[6] * 0.0625f, s[7] * 0.0625f};
    *(float4*)(out + (long)bt * 64 + d0) = o0;
    *(float4*)(out + (long)bt * 64 + d0 + 4) = o1;
}

// ---------------- reduce att_score partials over batch ----------------
__global__ void k_att_reduce(const float* __restrict__ part, float* __restrict__ out,
                             int n, int nb, long stride) {
    int i = blockIdx.x * blockDim.x + threadIdx.x;
    if (i >= n) return;
    float s = 0.f;
    for (int b = 0; b < nb; ++b) s += part[(long)b * stride + i];
    out[i] = s * (1.0f / 256.0f);
}

// ---------------- flash attention with log-size key bias ----------------
// grid: (ceil(T/64), H, B), block 256 (4 waves x 16 q-rows)
__global__ __launch_bounds__(256) void k_flash(
    const short* __restrict__ Q, const short* __restrict__ Kb, const short* __restrict__ Vb,
    const float* __restrict__ logsz, short* __restrict__ Ctx,
    int B, int T, int E, int H, int SP) {
    int b = blockIdx.z, h = blockIdx.y, t0 = blockIdx.x * 64;
    __shared__ short Qs[64][72];
    __shared__ short Ks[64][72];
    __shared__ short Vt[64][72];   // transposed: Vt[d][s]
    __shared__ short Ps[4][16][72];
    __shared__ float Ls[64];
    int tid = threadIdx.x, wid = tid >> 6, lane = tid & 63;
    int lr = lane & 15, lg = lane >> 4;
    const short* qb = Q + ((long)b * T + t0) * E + h * 64;
    for (int c = tid; c < 512; c += 256) {
        int r = c >> 3, d0 = (c & 7) * 8;
        s16x8 v = {0,0,0,0,0,0,0,0};
        if (t0 + r < T) v = *(const s16x8*)(qb + (long)r * E + d0);
        *(s16x8*)(&Qs[r][d0]) = v;
    }
    float m[4], l[4];
    f32x4 o[4];
    for (int q = 0; q < 4; q++) { m[q] = -INFINITY; l[q] = 0.f; }
    for (int jd = 0; jd < 4; jd++)
        for (int q = 0; q < 4; q++) o[jd][q] = 0.f;
    const short* kb = Kb + (long)b * T * E + h * 64;
    const short* vb = Vb + (long)b * T * E + h * 64;
    for (int s0 = 0; s0 < T; s0 += 64) {
        __syncthreads();
        for (int c = tid; c < 512; c += 256) {
            int r = c >> 3, d0 = (c & 7) * 8;
            s16x8 kv = {0,0,0,0,0,0,0,0}, vv = {0,0,0,0,0,0,0,0};
            if (s0 + r < T) {
                kv = *(const s16x8*)(kb + (long)(s0 + r) * E + d0);
                vv = *(const s16x8*)(vb + (long)(s0 + r) * E + d0);
            }
            *(s16x8*)(&Ks[r][d0]) = kv;
            for (int j = 0; j < 8; j++) Vt[d0 + j][r] = vv[j];
        }
        if (tid < 64) Ls[tid] = logsz[b * SP + s0 + tid];
        __syncthreads();
        f32x4 sf[4];
        for (int j = 0; j < 4; j++)
            for (int q = 0; q < 4; q++) sf[j][q] = 0.f;
        for (int ks = 0; ks < 2; ++ks) {
            s16x8 aq = *(const s16x8*)(&Qs[wid * 16 + lr][ks * 32 + lg * 8]);
            for (int j = 0; j < 4; j++) {
                s16x8 bk = *(const s16x8*)(&Ks[j * 16 + lr][ks * 32 + lg * 8]);
                sf[j] = MFMA16(aq, bk, sf[j]);
            }
        }
        float tmax[4];
        for (int q = 0; q < 4; q++) tmax[q] = -INFINITY;
        for (int j = 0; j < 4; j++) {
            float bl = Ls[j * 16 + lr];
            for (int q = 0; q < 4; q++) {
                sf[j][q] += bl;
                tmax[q] = fmaxf(tmax[q], sf[j][q]);
            }
        }
        for (int q = 0; q < 4; q++)
            for (int msk = 1; msk < 16; msk <<= 1)
                tmax[q] = fmaxf(tmax[q], __shfl_xor(tmax[q], msk));
        float al[4], rs[4];
        for (int q = 0; q < 4; q++) {
            float mn = fmaxf(m[q], tmax[q]);
            al[q] = __expf(m[q] - mn);
            m[q] = mn;
            rs[q] = 0.f;
        }
        for (int j = 0; j < 4; j++)
            for (int q = 0; q < 4; q++) {
                float p = __expf(sf[j][q] - m[q]);
                sf[j][q] = p;
                rs[q] += p;
            }
        for (int q = 0; q < 4; q++) {
            for (int msk = 1; msk < 16; msk <<= 1) rs[q] += __shfl_xor(rs[q], msk);
            l[q] = l[q] * al[q] + rs[q];
        }
        for (int jd = 0; jd < 4; jd++)
            for (int q = 0; q < 4; q++) o[jd][q] *= al[q];
        for (int j = 0; j < 4; j++)
            for (int q = 0; q < 4; q++)
                Ps[wid][lg * 4 + q][j * 16 + lr] = f2b(sf[j][q]);
        __syncthreads();
        for (int ks = 0; ks < 2; ++ks) {
            s16x8 ap = *(const s16x8*)(&Ps[wid][lr][ks * 32 + lg * 8]);
            for (int jd = 0; jd < 4; jd++) {
                s16x8 bv = *(const s16x8*)(&Vt[jd * 16 + lr][ks * 32 + lg * 8]);
                o[jd] = MFMA16(ap, bv, o[jd]);
            }
        }
    }
    short* cb = Ctx + ((long)b * T + t0) * E + h * 64;
    for (int q = 0; q < 4; q++) {
        int t = wid * 16 + lg * 4 + q;
        if (t0 + t >= T) continue;
        float inv = 1.f / l[q];
        for (int jd = 0; jd < 4; jd++)
            cb[(long)t * E + jd * 16 + lr] = f2b(o[jd][q] * inv);
    }
}

extern "C" void kernel_launch(void* const* d_in, const int* in_sizes, int n_in,
                              void* d_out, int out_size, void* d_ws, size_t ws_size,
                              hipStream_t stream) {
    (void)in_sizes; (void)n_in; (void)out_size; (void)ws_size;
    const int B = 16, T = 577, E = 1024, H = 16, D = 64;
    const int SP = 640;
    const float* hs   = (const float*)d_in[0];
    const float* size = (const float*)d_in[1];
    const float* wq   = (const float*)d_in[2];
    const float* bq   = (const float*)d_in[3];
    const float* wk   = (const float*)d_in[4];
    const float* bk   = (const float*)d_in[5];
    const float* wv   = (const float*)d_in[6];
    const float* bv   = (const float*)d_in[7];
    const float* wo   = (const float*)d_in[8];
    const float* bo   = (const float*)d_in[9];

    float* out_attn = (float*)d_out;                  // B*T*E
    float* out_mk   = out_attn + (long)B * T * E;     // B*T*D
    float* out_as   = out_mk + (long)B * T * D;       // T*T

    long nBTE = (long)B * T * E;
    long nEE  = (long)E * E;
    char* ws = (char*)d_ws;
    short* hs_b  = (short*)ws; ws += nBTE * 2;
    short* wq_b  = (short*)ws; ws += nEE * 2;
    short* wk_b  = (short*)ws; ws += nEE * 2;
    short* wv_b  = (short*)ws; ws += nEE * 2;
    short* wo_b  = (short*)ws; ws += nEE * 2;
    short* q_b   = (short*)ws; ws += nBTE * 2;
    short* k_b   = (short*)ws; ws += nBTE * 2;
    short* v_b   = (short*)ws; ws += nBTE * 2;
    short* ctx_b = (short*)ws; ws += nBTE * 2;
    float* logsz = (float*)ws; ws += (long)B * SP * 4;
    float* att_p = (float*)ws; ws += (long)B * T * T * 4;

    // converts
    k_f32_to_bf16<<<2048, 256, 0, stream>>>(hs, hs_b, nBTE);
    k_f32_to_bf16<<<1024, 256, 0, stream>>>(wq, wq_b, nEE);
    k_f32_to_bf16<<<1024, 256, 0, stream>>>(wk, wk_b, nEE);
    k_f32_to_bf16<<<1024, 256, 0, stream>>>(wv, wv_b, nEE);
    k_f32_to_bf16<<<1024, 256, 0, stream>>>(wo, wo_b, nEE);
    k_logsize<<<(B * SP + 255) / 256, 256, 0, stream>>>(size, logsz, B, T, SP);

    int M = B * T;
    dim3 blk(256);
    // fused QKV projections (one dispatch)
    dim3 g_qkv(E / 128, (M + 127) / 128, 3);
    k_qkv<<<g_qkv, blk, 0, stream>>>(hs_b, wq_b, wk_b, wv_b, bq, bk, bv,
                                     q_b, k_b, v_b, M, E);

    // att_score partials + deterministic reduce
    dim3 g_att((T + 127) / 128, (T + 127) / 128, B);
    k_att<<<g_att, blk, 0, stream>>>(q_b, k_b, att_p, T, E);
    k_att_reduce<<<((T * T) + 255) / 256, 256, 0, stream>>>(att_p, out_as, T * T, B, (long)T * T);

    // mean over heads of K
    k_mean_keys8<<<((B * T * 8) + 255) / 256, 256, 0, stream>>>(k_b, out_mk, B * T);

    // flash attention -> context (bf16)
    dim3 g_fl((T + 63) / 64, H, B);
    k_flash<<<g_fl, blk, 0, stream>>>(q_b, k_b, v_b, logsz, ctx_b, B, T, E, H, SP);

    // output projection -> fp32 d_out
    dim3 g_proj(E / 128, (M + 127) / 128, 1);
    k_proj<<<g_proj, blk, 0, stream>>>(ctx_b, wo_b, bo, out_attn, M, E);
}

// Round 3
// 384.809 us; speedup vs baseline: 3.8278x; 1.0097x over previous
//
#include <hip/hip_runtime.h>
#include <hip/hip_bf16.h>
#include <math.h>

typedef __attribute__((ext_vector_type(8))) short s16x8;
typedef __attribute__((ext_vector_type(4))) short s16x4;
typedef __attribute__((ext_vector_type(4))) float f32x4;
typedef __attribute__((ext_vector_type(8))) __bf16 bf16x8;

#define MFMA16(a, b, c) __builtin_amdgcn_mfma_f32_16x16x32_bf16( \
    __builtin_bit_cast(bf16x8, (a)), __builtin_bit_cast(bf16x8, (b)), (c), 0, 0, 0)

__device__ __forceinline__ short f2b(float f) {
    union { float f; unsigned u; } x; x.f = f;
    unsigned u = x.u;
    unsigned r = (u + 0x7FFFu + ((u >> 16) & 1u)) >> 16;
    return (short)r;
}
__device__ __forceinline__ float b2f(short b) {
    union { unsigned u; float f; } x;
    x.u = ((unsigned)(unsigned short)b) << 16;
    return x.f;
}

__device__ __forceinline__ void gload16(const void* g, void* l) {
    __builtin_amdgcn_global_load_lds(
        (const __attribute__((address_space(1))) unsigned int*)g,
        (__attribute__((address_space(3))) unsigned int*)l, 16, 0, 0);
}

// ---------------- fp32 -> bf16 convert (vectorized, grid-stride) ----------------
__global__ void k_f32_to_bf16(const float* __restrict__ in, short* __restrict__ out, long n) {
    long i = ((long)blockIdx.x * blockDim.x + threadIdx.x) * 4;
    long stride = (long)gridDim.x * blockDim.x * 4;
    for (; i < n; i += stride) {
        float4 v = *(const float4*)(in + i);
        s16x4 o = { f2b(v.x), f2b(v.y), f2b(v.z), f2b(v.w) };
        *(s16x4*)(out + i) = o;
    }
}

// ---------------- log(size) with -inf-ish padding ----------------
__global__ void k_logsize(const float* __restrict__ size, float* __restrict__ out,
                          int B, int T, int SP) {
    int i = blockIdx.x * blockDim.x + threadIdx.x;
    if (i >= B * SP) return;
    int b = i / SP, s = i % SP;
    out[i] = (s < T) ? logf(size[b * T + s]) : -1e30f;
}

// ---------------- m97-style GEMM core: C = (A @ B^T + bias) * alpha ----------------
__device__ __forceinline__ void gemm_core(
    const short* __restrict__ Ab, const short* __restrict__ Bb,
    const float* __restrict__ bias, float alpha,
    short* __restrict__ Cb, float* __restrict__ Cf,
    int M, int N, int K, int ldc, int row0, int col0) {
    __shared__ short As[128 * 64];
    __shared__ short Bs[128 * 64];
    int tid = threadIdx.x;
    int lane = tid & 63, wave = tid >> 6;
    int wr = wave >> 1, wc = wave & 1;
    int lr = lane & 15, lg = lane >> 4;
    f32x4 acc[4][4];
    #pragma unroll
    for (int i = 0; i < 4; i++)
        #pragma unroll
        for (int j = 0; j < 4; j++)
            #pragma unroll
            for (int q = 0; q < 4; q++) acc[i][j][q] = 0.f;

    for (int k0 = 0; k0 < K; k0 += 64) {
        __syncthreads();
        #pragma unroll
        for (int i = 0; i < 4; ++i) {
            int cw = i * 256 + wave * 64;
            int c = cw + lane;
            int r = c >> 3;
            int cs = (c & 7) * 8;
            int ra = row0 + r; ra = ra < M ? ra : M - 1;
            gload16(Ab + (long)ra * K + k0 + cs, &As[cw * 8]);
            int rb = col0 + r; rb = rb < N ? rb : N - 1;
            gload16(Bb + (long)rb * K + k0 + cs, &Bs[cw * 8]);
        }
        __syncthreads();
        #pragma unroll
        for (int ks = 0; ks < 2; ++ks) {
            s16x8 af[4], bfr[4];
            #pragma unroll
            for (int i = 0; i < 4; ++i)
                af[i] = *(const s16x8*)&As[(wr * 64 + i * 16 + lr) * 64 + ks * 32 + lg * 8];
            #pragma unroll
            for (int j = 0; j < 4; ++j)
                bfr[j] = *(const s16x8*)&Bs[(wc * 64 + j * 16 + lr) * 64 + ks * 32 + lg * 8];
            #pragma unroll
            for (int i = 0; i < 4; ++i)
                #pragma unroll
                for (int j = 0; j < 4; ++j)
                    acc[i][j] = MFMA16(af[i], bfr[j], acc[i][j]);
        }
    }
    #pragma unroll
    for (int i = 0; i < 4; i++) {
        int rbase = row0 + wr * 64 + i * 16 + lg * 4;
        #pragma unroll
        for (int j = 0; j < 4; j++) {
            int c = col0 + wc * 64 + j * 16 + lr;
            if (c >= N) continue;
            float bv = bias ? bias[c] : 0.f;
            #pragma unroll
            for (int q = 0; q < 4; q++) {
                int r = rbase + q;
                if (r >= M) continue;
                float y = (acc[i][j][q] + bv) * alpha;
                long off = (long)r * ldc + c;
                if (Cb) Cb[off] = f2b(y);
                else    Cf[off] = y;
            }
        }
    }
}

__global__ __launch_bounds__(256) void k_qkv(
    const short* __restrict__ hs,
    const short* __restrict__ wq, const short* __restrict__ wk, const short* __restrict__ wv,
    const float* __restrict__ bq, const float* __restrict__ bk, const float* __restrict__ bv,
    short* __restrict__ q, short* __restrict__ k, short* __restrict__ v,
    int M, int E) {
    int z = blockIdx.z;
    const short* W = (z == 0) ? wq : (z == 1) ? wk : wv;
    const float* bi = (z == 0) ? bq : (z == 1) ? bk : bv;
    short* C = (z == 0) ? q : (z == 1) ? k : v;
    float alpha = (z == 0) ? 0.125f : 1.0f;
    gemm_core(hs, W, bi, alpha, C, nullptr, M, E, E, E,
              blockIdx.y * 128, blockIdx.x * 128);
}

__global__ __launch_bounds__(256) void k_att(
    const short* __restrict__ q, const short* __restrict__ k,
    float* __restrict__ attp, int T, int E) {
    int z = blockIdx.z;
    gemm_core(q + (long)z * T * E, k + (long)z * T * E, nullptr, 1.0f,
              nullptr, attp + (long)z * T * T, T, T, E, T,
              blockIdx.y * 128, blockIdx.x * 128);
}

__global__ __launch_bounds__(256) void k_proj(
    const short* __restrict__ ctx, const short* __restrict__ wo,
    const float* __restrict__ bo, float* __restrict__ out, int M, int E) {
    gemm_core(ctx, wo, bo, 1.0f, nullptr, out, M, E, E, E,
              blockIdx.y * 128, blockIdx.x * 128);
}

// ---------------- mean over heads of K (vectorized): [B,T,D] ----------------
__global__ void k_mean_keys8(const short* __restrict__ Kb, float* __restrict__ out, int BT) {
    int i = blockIdx.x * blockDim.x + threadIdx.x;
    if (i >= BT * 8) return;
    int bt = i >> 3, d0 = (i & 7) * 8;
    const short* p = Kb + (long)bt * 1024 + d0;
    float s[8] = {0.f, 0.f, 0.f, 0.f, 0.f, 0.f, 0.f, 0.f};
    #pragma unroll
    for (int h = 0; h < 16; ++h) {
        s16x8 v = *(const s16x8*)(p + h * 64);
        #pragma unroll
        for (int j = 0; j < 8; ++j) s[j] += b2f(v[j]);
    }
    float4 o0 = {s[0] * 0.0625f, s[1] * 0.0625f, s[2] * 0.0625f, s[3] * 0.0625f};
    float4 o1 = {s[4] * 0.0625f, s[5] * 0.0625f, s[6] * 0.0625f, s[7] * 0.0625f};
    *(float4*)(out + (long)bt * 64 + d0) = o0;
    *(float4*)(out + (long)bt * 64 + d0 + 4) = o1;
}

// ---------------- reduce att_score partials over batch ----------------
__global__ void k_att_reduce(const float* __restrict__ part, float* __restrict__ out,
                             int n, int nb, long stride) {
    int i = blockIdx.x * blockDim.x + threadIdx.x;
    if (i >= n) return;
    float s = 0.f;
    for (int b = 0; b < nb; ++b) s += part[(long)b * stride + i];
    out[i] = s * (1.0f / 256.0f);
}

// ---------------- V transpose: v[B,T,H*64] -> vt[B*H][64][TP] (pad t with 0) ----------------
__global__ __launch_bounds__(256) void k_vtrans(const short* __restrict__ v, short* __restrict__ vt,
                                                int B, int T, int H, int TP) {
    int b = blockIdx.z, h = blockIdx.y, t0 = blockIdx.x * 64;
    __shared__ short Vs[64][68];
    int tid = threadIdx.x;
    for (int c = tid; c < 512; c += 256) {
        int r = c >> 3, m = c & 7;
        s16x8 val = {0,0,0,0,0,0,0,0};
        if (t0 + r < T) val = *(const s16x8*)(v + ((long)(b * T + t0 + r)) * (H * 64) + h * 64 + m * 8);
        *(s16x8*)&Vs[r][m * 8] = val;
    }
    __syncthreads();
    for (int c = tid; c < 512; c += 256) {
        int d = c >> 3, mw = c & 7;
        s16x8 o;
        #pragma unroll
        for (int j = 0; j < 8; j++) o[j] = Vs[mw * 8 + j][d];
        *(s16x8*)(vt + ((long)((b * H + h) * 64 + d)) * TP + t0 + mw * 8) = o;
    }
}

// ---------------- flash attention v2: QBLK=128, padded LDS, pre-transposed V ----------------
// flat grid 1280 blocks, XCD-chunked swizzle; 4 waves x 32 q-rows
__global__ __launch_bounds__(256) void k_flash(
    const short* __restrict__ Q, const short* __restrict__ Kb, const short* __restrict__ VT,
    const float* __restrict__ logsz, short* __restrict__ Ctx,
    int B, int T, int E, int H, int SP, int TP, int NTQ) {
    // XCD-chunked bijective swizzle (grid % 8 == 0)
    int nwg = gridDim.x;
    int cpx = nwg >> 3;
    int wg = (blockIdx.x & 7) * cpx + (blockIdx.x >> 3);
    int tq = wg % NTQ, h = (wg / NTQ) % H, b = wg / (NTQ * H);
    int t0 = tq * 128;

    __shared__ short Qs[128][68];
    __shared__ short Ks[64][68];
    __shared__ short Vt[64][68];
    __shared__ short Ps[4][32][68];
    __shared__ float Ls[64];
    int tid = threadIdx.x, wid = tid >> 6, lane = tid & 63;
    int lr = lane & 15, lg = lane >> 4;

    // stage Q (128 rows x 64 d)
    for (int c = tid; c < 1024; c += 256) {
        int r = c >> 3, m = c & 7;
        int t = t0 + r; t = t < T ? t : T - 1;
        s16x8 v = *(const s16x8*)(Q + ((long)b * T + t) * E + h * 64 + m * 8);
        *(s16x8*)&Qs[r][m * 8] = v;
    }

    float mreg[2][4], lsum[2][4];
    f32x4 o[2][4];
    #pragma unroll
    for (int i = 0; i < 2; i++)
        #pragma unroll
        for (int q = 0; q < 4; q++) { mreg[i][q] = -INFINITY; lsum[i][q] = 0.f; }
    #pragma unroll
    for (int i = 0; i < 2; i++)
        #pragma unroll
        for (int jd = 0; jd < 4; jd++)
            #pragma unroll
            for (int q = 0; q < 4; q++) o[i][jd][q] = 0.f;

    const short* kb = Kb + (long)b * T * E + h * 64;
    const short* vtb = VT + ((long)(b * H + h)) * 64 * TP;

    for (int s0 = 0; s0 < T; s0 += 64) {
        __syncthreads();
        for (int c = tid; c < 512; c += 256) {
            int r = c >> 3, m = c & 7;
            int s = s0 + r; s = s < T ? s : T - 1;
            *(s16x8*)&Ks[r][m * 8] = *(const s16x8*)(kb + (long)s * E + m * 8);
            *(s16x8*)&Vt[r][m * 8] = *(const s16x8*)(vtb + (long)r * TP + s0 + m * 8);
        }
        if (tid < 64) Ls[tid] = logsz[b * SP + s0 + tid];
        __syncthreads();

        // cache K fragments (reused for both 16-row q groups)
        s16x8 kf[2][4];
        #pragma unroll
        for (int ks = 0; ks < 2; ++ks)
            #pragma unroll
            for (int j = 0; j < 4; ++j)
                kf[ks][j] = *(const s16x8*)&Ks[j * 16 + lr][ks * 32 + lg * 8];

        #pragma unroll
        for (int i = 0; i < 2; ++i) {
            f32x4 sf[4];
            #pragma unroll
            for (int j = 0; j < 4; j++)
                #pragma unroll
                for (int q = 0; q < 4; q++) sf[j][q] = 0.f;
            __builtin_amdgcn_s_setprio(1);
            #pragma unroll
            for (int ks = 0; ks < 2; ++ks) {
                s16x8 aq = *(const s16x8*)&Qs[wid * 32 + i * 16 + lr][ks * 32 + lg * 8];
                #pragma unroll
                for (int j = 0; j < 4; j++) sf[j] = MFMA16(aq, kf[ks][j], sf[j]);
            }
            __builtin_amdgcn_s_setprio(0);

            // online softmax (rows = lg*4+q, cols = j*16+lr)
            float tmax[4] = {-INFINITY, -INFINITY, -INFINITY, -INFINITY};
            #pragma unroll
            for (int j = 0; j < 4; j++) {
                float bl = Ls[j * 16 + lr];
                #pragma unroll
                for (int q = 0; q < 4; q++) {
                    sf[j][q] += bl;
                    tmax[q] = fmaxf(tmax[q], sf[j][q]);
                }
            }
            #pragma unroll
            for (int q = 0; q < 4; q++)
                #pragma unroll
                for (int msk = 1; msk < 16; msk <<= 1)
                    tmax[q] = fmaxf(tmax[q], __shfl_xor(tmax[q], msk));
            float al[4], rs[4];
            #pragma unroll
            for (int q = 0; q < 4; q++) {
                float mn = fmaxf(mreg[i][q], tmax[q]);
                al[q] = __expf(mreg[i][q] - mn);
                mreg[i][q] = mn;
                rs[q] = 0.f;
            }
            #pragma unroll
            for (int j = 0; j < 4; j++)
                #pragma unroll
                for (int q = 0; q < 4; q++) {
                    float p = __expf(sf[j][q] - mreg[i][q]);
                    sf[j][q] = p;
                    rs[q] += p;
                }
            #pragma unroll
            for (int q = 0; q < 4; q++) {
                #pragma unroll
                for (int msk = 1; msk < 16; msk <<= 1) rs[q] += __shfl_xor(rs[q], msk);
                lsum[i][q] = lsum[i][q] * al[q] + rs[q];
            }
            #pragma unroll
            for (int jd = 0; jd < 4; jd++)
                #pragma unroll
                for (int q = 0; q < 4; q++) o[i][jd][q] *= al[q];

            // P -> LDS (wave-private, conflict-free stride-68)
            #pragma unroll
            for (int j = 0; j < 4; j++)
                #pragma unroll
                for (int q = 0; q < 4; q++)
                    Ps[wid][i * 16 + lg * 4 + q][j * 16 + lr] = f2b(sf[j][q]);

            // PV
            __builtin_amdgcn_s_setprio(1);
            #pragma unroll
            for (int ks = 0; ks < 2; ++ks) {
                s16x8 ap = *(const s16x8*)&Ps[wid][i * 16 + lr][ks * 32 + lg * 8];
                #pragma unroll
                for (int jd = 0; jd < 4; jd++) {
                    s16x8 bv = *(const s16x8*)&Vt[jd * 16 + lr][ks * 32 + lg * 8];
                    o[i][jd] = MFMA16(ap, bv, o[i][jd]);
                }
            }
            __builtin_amdgcn_s_setprio(0);
        }
    }

    short* cb = Ctx + ((long)b * T + t0) * E + h * 64;
    #pragma unroll
    for (int i = 0; i < 2; i++)
        #pragma unroll
        for (int q = 0; q < 4; q++) {
            int t = wid * 32 + i * 16 + lg * 4 + q;
            if (t0 + t >= T) continue;
            float inv = 1.f / lsum[i][q];
            #pragma unroll
            for (int jd = 0; jd < 4; jd++)
                cb[(long)t * E + jd * 16 + lr] = f2b(o[i][jd][q] * inv);
        }
}

extern "C" void kernel_launch(void* const* d_in, const int* in_sizes, int n_in,
                              void* d_out, int out_size, void* d_ws, size_t ws_size,
                              hipStream_t stream) {
    (void)in_sizes; (void)n_in; (void)out_size; (void)ws_size;
    const int B = 16, T = 577, E = 1024, H = 16, D = 64;
    const int SP = 640, TP = 640;
    const float* hs   = (const float*)d_in[0];
    const float* size = (const float*)d_in[1];
    const float* wq   = (const float*)d_in[2];
    const float* bq   = (const float*)d_in[3];
    const float* wk   = (const float*)d_in[4];
    const float* bk   = (const float*)d_in[5];
    const float* wv   = (const float*)d_in[6];
    const float* bv   = (const float*)d_in[7];
    const float* wo   = (const float*)d_in[8];
    const float* bo   = (const float*)d_in[9];

    float* out_attn = (float*)d_out;                  // B*T*E
    float* out_mk   = out_attn + (long)B * T * E;     // B*T*D
    float* out_as   = out_mk + (long)B * T * D;       // T*T

    long nBTE = (long)B * T * E;
    long nEE  = (long)E * E;
    char* ws = (char*)d_ws;
    short* hs_b  = (short*)ws; ws += nBTE * 2;
    short* wq_b  = (short*)ws; ws += nEE * 2;
    short* wk_b  = (short*)ws; ws += nEE * 2;
    short* wv_b  = (short*)ws; ws += nEE * 2;
    short* wo_b  = (short*)ws; ws += nEE * 2;
    short* q_b   = (short*)ws; ws += nBTE * 2;
    short* k_b   = (short*)ws; ws += nBTE * 2;
    short* v_b   = (short*)ws; ws += nBTE * 2;
    short* ctx_b = (short*)ws; ws += nBTE * 2;
    float* logsz = (float*)ws; ws += (long)B * SP * 4;
    float* att_p = (float*)ws; ws += (long)B * T * T * 4;
    // vt aliases att_p: written only AFTER k_att_reduce consumed att_p
    // (stream-ordered). vt bytes = B*H*64*TP*2 = 21.0MB <= att_p 21.3MB.
    short* vt = (short*)att_p;

    k_f32_to_bf16<<<2048, 256, 0, stream>>>(hs, hs_b, nBTE);
    k_f32_to_bf16<<<1024, 256, 0, stream>>>(wq, wq_b, nEE);
    k_f32_to_bf16<<<1024, 256, 0, stream>>>(wk, wk_b, nEE);
    k_f32_to_bf16<<<1024, 256, 0, stream>>>(wv, wv_b, nEE);
    k_f32_to_bf16<<<1024, 256, 0, stream>>>(wo, wo_b, nEE);
    k_logsize<<<(B * SP + 255) / 256, 256, 0, stream>>>(size, logsz, B, T, SP);

    int M = B * T;
    dim3 blk(256);
    dim3 g_qkv(E / 128, (M + 127) / 128, 3);
    k_qkv<<<g_qkv, blk, 0, stream>>>(hs_b, wq_b, wk_b, wv_b, bq, bk, bv,
                                     q_b, k_b, v_b, M, E);

    dim3 g_att((T + 127) / 128, (T + 127) / 128, B);
    k_att<<<g_att, blk, 0, stream>>>(q_b, k_b, att_p, T, E);
    k_att_reduce<<<((T * T) + 255) / 256, 256, 0, stream>>>(att_p, out_as, T * T, B, (long)T * T);

    // transpose V (after att_p consumed; vt aliases it)
    dim3 g_vt((T + 63) / 64, H, B);
    k_vtrans<<<g_vt, blk, 0, stream>>>(v_b, vt, B, T, H, TP);

    k_mean_keys8<<<((B * T * 8) + 255) / 256, 256, 0, stream>>>(k_b, out_mk, B * T);

    // flash attention: flat grid, XCD swizzle (1280 % 8 == 0)
    const int NTQ = (T + 127) / 128;
    int nfl = NTQ * H * B;
    k_flash<<<nfl, blk, 0, stream>>>(q_b, k_b, vt, logsz, ctx_b, B, T, E, H, SP, TP, NTQ);

    dim3 g_proj(E / 128, (M + 127) / 128, 1);
    k_proj<<<g_proj, blk, 0, stream>>>(ctx_b, wo_b, bo, out_attn, M, E);
}

// Round 4
// 366.503 us; speedup vs baseline: 4.0190x; 1.0499x over previous
//
#include <hip/hip_runtime.h>
#include <hip/hip_bf16.h>
#include <math.h>

typedef __attribute__((ext_vector_type(8))) short s16x8;
typedef __attribute__((ext_vector_type(4))) short s16x4;
typedef __attribute__((ext_vector_type(4))) float f32x4;
typedef __attribute__((ext_vector_type(8))) __bf16 bf16x8;

#define MFMA16(a, b, c) __builtin_amdgcn_mfma_f32_16x16x32_bf16( \
    __builtin_bit_cast(bf16x8, (a)), __builtin_bit_cast(bf16x8, (b)), (c), 0, 0, 0)

__device__ __forceinline__ short f2b(float f) {
    union { float f; unsigned u; } x; x.f = f;
    unsigned u = x.u;
    unsigned r = (u + 0x7FFFu + ((u >> 16) & 1u)) >> 16;
    return (short)r;
}
__device__ __forceinline__ float b2f(short b) {
    union { unsigned u; float f; } x;
    x.u = ((unsigned)(unsigned short)b) << 16;
    return x.f;
}

__device__ __forceinline__ void gload16(const void* g, void* l) {
    __builtin_amdgcn_global_load_lds(
        (const __attribute__((address_space(1))) unsigned int*)g,
        (__attribute__((address_space(3))) unsigned int*)l, 16, 0, 0);
}

// ---------------- fp32 -> bf16 convert ----------------
__global__ void k_f32_to_bf16(const float* __restrict__ in, short* __restrict__ out, long n) {
    long i = ((long)blockIdx.x * blockDim.x + threadIdx.x) * 4;
    long stride = (long)gridDim.x * blockDim.x * 4;
    for (; i < n; i += stride) {
        float4 v = *(const float4*)(in + i);
        s16x4 o = { f2b(v.x), f2b(v.y), f2b(v.z), f2b(v.w) };
        *(s16x4*)(out + i) = o;
    }
}

// ---------------- log(size) with padding ----------------
__global__ void k_logsize(const float* __restrict__ size, float* __restrict__ out,
                          int B, int T, int SP) {
    int i = blockIdx.x * blockDim.x + threadIdx.x;
    if (i >= B * SP) return;
    int b = i / SP, s = i % SP;
    out[i] = (s < T) ? logf(size[b * T + s]) : -1e30f;
}

// ================= 256x256 8-wave phase-pipelined GEMM (C = A @ B^T) =================
// LDS swizzle: LDS[r][inner] = G[r][inner ^ ((r&7)<<4)]; read applies same XOR.
__device__ __forceinline__ void stage_half(const short* __restrict__ src, int ldk,
                                           int row0, int maxrow, int k0,
                                           short* lds, int tid) {
    #pragma unroll
    for (int j = 0; j < 2; ++j) {
        int ch = tid + j * 512;
        int r = ch >> 3;
        int cby = ((ch & 7) * 16) ^ ((r & 7) << 4);   // pre-swizzled source byte col
        int gr = row0 + r; gr = gr < maxrow ? gr : maxrow - 1;
        gload16((const char*)(src + (long)gr * ldk + k0) + cby,
                (char*)lds + ch * 16);
    }
}

__device__ __forceinline__ s16x8 lds_frag(const short* half, int r, int ks, int lg) {
    int cby = ((ks << 6) + (lg << 4)) ^ ((r & 7) << 4);
    return *(const s16x8*)((const char*)half + r * 128 + cby);
}

template<bool ROUTE>
__global__ __launch_bounds__(512, 2) void k_gemm8(
    const short* __restrict__ A, const short* __restrict__ Bw,
    const float* __restrict__ bb0, const float* __restrict__ bb1, const float* __restrict__ bb2,
    short* __restrict__ o0, short* __restrict__ o1, short* __restrict__ o2,
    float* __restrict__ Cf, int M, int N, int K, int Ntiles) {

    __shared__ short AS[2][2][128 * 64];
    __shared__ short BS[2][2][128 * 64];

    // bijective XCD-chunked swizzle (m204 formula; works for any nwg)
    int nwg = gridDim.x, orig = blockIdx.x;
    int qq = nwg >> 3, rr = nwg & 7;
    int xcd = orig & 7, pos = orig >> 3;
    int wg = (xcd < rr ? xcd * (qq + 1) : rr * (qq + 1) + (xcd - rr) * qq) + pos;
    int bx = wg % Ntiles, by = wg / Ntiles;
    int row0 = by * 256, col0 = bx * 256;

    int tid = threadIdx.x;
    int lane = tid & 63, wave = tid >> 6;
    int wm = wave >> 2, wn = wave & 3;          // 2 m-waves x 4 n-waves
    int lr = lane & 15, lg = lane >> 4;
    int bh = wn >> 1, brb = (wn & 1) * 64;      // B half index, row base in half

    f32x4 acc[8][4];
    #pragma unroll
    for (int i = 0; i < 8; i++)
        #pragma unroll
        for (int j = 0; j < 4; j++)
            #pragma unroll
            for (int q = 0; q < 4; q++) acc[i][j][q] = 0.f;

    int nt = K >> 6;
    // prologue: stage tile 0 into buf 0
    stage_half(A,  K, row0,       M, 0, AS[0][0], tid);
    stage_half(A,  K, row0 + 128, M, 0, AS[0][1], tid);
    stage_half(Bw, K, col0,       N, 0, BS[0][0], tid);
    stage_half(Bw, K, col0 + 128, N, 0, BS[0][1], tid);

    for (int t = 0; t < nt; ++t) {
        int cur = t & 1;
        asm volatile("s_waitcnt vmcnt(0)" ::: "memory");  // tile-t halves issued >=2 phases ago
        __builtin_amdgcn_s_barrier();                      // make all waves' DMA visible
        const short* Ah = AS[cur][wm];
        const short* Bh = BS[cur][bh];
        s16x8 bf[4][2];
        #pragma unroll
        for (int p = 0; p < 4; ++p) {
            if (t + 1 < nt) {                 // prefetch next tile early (phases 0,1)
                int k1 = (t + 1) << 6;
                if (p == 0) {
                    stage_half(A, K, row0,       M, k1, AS[cur ^ 1][0], tid);
                    stage_half(A, K, row0 + 128, M, k1, AS[cur ^ 1][1], tid);
                } else if (p == 1) {
                    stage_half(Bw, K, col0,       N, k1, BS[cur ^ 1][0], tid);
                    stage_half(Bw, K, col0 + 128, N, k1, BS[cur ^ 1][1], tid);
                }
            }
            if (p == 0) {
                #pragma unroll
                for (int nf = 0; nf < 4; ++nf)
                    #pragma unroll
                    for (int ks = 0; ks < 2; ++ks)
                        bf[nf][ks] = lds_frag(Bh, brb + nf * 16 + lr, ks, lg);
            }
            s16x8 af[2][2];
            #pragma unroll
            for (int i = 0; i < 2; ++i)
                #pragma unroll
                for (int ks = 0; ks < 2; ++ks)
                    af[i][ks] = lds_frag(Ah, (2 * p + i) * 16 + lr, ks, lg);
            __builtin_amdgcn_s_setprio(1);
            #pragma unroll
            for (int i = 0; i < 2; ++i)
                #pragma unroll
                for (int nf = 0; nf < 4; ++nf)
                    #pragma unroll
                    for (int ks = 0; ks < 2; ++ks)
                        acc[2 * p + i][nf] = MFMA16(af[i][ks], bf[nf][ks], acc[2 * p + i][nf]);
            __builtin_amdgcn_s_setprio(0);
            __builtin_amdgcn_s_barrier();
        }
    }

    // epilogue
    int wrow = row0 + wm * 128;
    #pragma unroll
    for (int mf = 0; mf < 8; ++mf) {
        int grow = wrow + mf * 16 + lg * 4;
        #pragma unroll
        for (int nf = 0; nf < 4; ++nf) {
            int gc = col0 + wn * 64 + nf * 16 + lr;
            if (gc >= N) continue;
            if (ROUTE) {
                int which = gc >> 10, lc = gc & 1023;
                float bias = (which == 0 ? bb0 : which == 1 ? bb1 : bb2)[lc];
                float alpha = (which == 0) ? 0.125f : 1.0f;
                short* op = (which == 0 ? o0 : which == 1 ? o1 : o2);
                #pragma unroll
                for (int q = 0; q < 4; ++q) {
                    int r2 = grow + q;
                    if (r2 < M) op[(long)r2 * 1024 + lc] = f2b((acc[mf][nf][q] + bias) * alpha);
                }
            } else {
                float bias = bb0[gc];
                #pragma unroll
                for (int q = 0; q < 4; ++q) {
                    int r2 = grow + q;
                    if (r2 < M) Cf[(long)r2 * N + gc] = acc[mf][nf][q] + bias;
                }
            }
        }
    }
}

// ---------------- old 128^2 core (kept for att partials) ----------------
__device__ __forceinline__ void gemm_core(
    const short* __restrict__ Ab, const short* __restrict__ Bb,
    float* __restrict__ Cf, int M, int N, int K, int ldc, int row0, int col0) {
    __shared__ short As[128 * 64];
    __shared__ short Bs[128 * 64];
    int tid = threadIdx.x;
    int lane = tid & 63, wave = tid >> 6;
    int wr = wave >> 1, wc = wave & 1;
    int lr = lane & 15, lg = lane >> 4;
    f32x4 acc[4][4];
    #pragma unroll
    for (int i = 0; i < 4; i++)
        #pragma unroll
        for (int j = 0; j < 4; j++)
            #pragma unroll
            for (int q = 0; q < 4; q++) acc[i][j][q] = 0.f;

    for (int k0 = 0; k0 < K; k0 += 64) {
        __syncthreads();
        #pragma unroll
        for (int i = 0; i < 4; ++i) {
            int cw = i * 256 + wave * 64;
            int c = cw + lane;
            int r = c >> 3;
            int cs = (c & 7) * 8;
            int ra = row0 + r; ra = ra < M ? ra : M - 1;
            gload16(Ab + (long)ra * K + k0 + cs, &As[cw * 8]);
            int rb = col0 + r; rb = rb < N ? rb : N - 1;
            gload16(Bb + (long)rb * K + k0 + cs, &Bs[cw * 8]);
        }
        __syncthreads();
        #pragma unroll
        for (int ks = 0; ks < 2; ++ks) {
            s16x8 af[4], bfr[4];
            #pragma unroll
            for (int i = 0; i < 4; ++i)
                af[i] = *(const s16x8*)&As[(wr * 64 + i * 16 + lr) * 64 + ks * 32 + lg * 8];
            #pragma unroll
            for (int j = 0; j < 4; ++j)
                bfr[j] = *(const s16x8*)&Bs[(wc * 64 + j * 16 + lr) * 64 + ks * 32 + lg * 8];
            #pragma unroll
            for (int i = 0; i < 4; ++i)
                #pragma unroll
                for (int j = 0; j < 4; ++j)
                    acc[i][j] = MFMA16(af[i], bfr[j], acc[i][j]);
        }
    }
    #pragma unroll
    for (int i = 0; i < 4; i++) {
        int rbase = row0 + wr * 64 + i * 16 + lg * 4;
        #pragma unroll
        for (int j = 0; j < 4; j++) {
            int c = col0 + wc * 64 + j * 16 + lr;
            if (c >= N) continue;
            #pragma unroll
            for (int q = 0; q < 4; q++) {
                int r = rbase + q;
                if (r >= M) continue;
                Cf[(long)r * ldc + c] = acc[i][j][q];
            }
        }
    }
}

__global__ __launch_bounds__(256) void k_att(
    const short* __restrict__ q, const short* __restrict__ k,
    float* __restrict__ attp, int T, int E) {
    int z = blockIdx.z;
    gemm_core(q + (long)z * T * E, k + (long)z * T * E,
              attp + (long)z * T * T, T, T, E, T,
              blockIdx.y * 128, blockIdx.x * 128);
}

// ---------------- mean over heads of K ----------------
__global__ void k_mean_keys8(const short* __restrict__ Kb, float* __restrict__ out, int BT) {
    int i = blockIdx.x * blockDim.x + threadIdx.x;
    if (i >= BT * 8) return;
    int bt = i >> 3, d0 = (i & 7) * 8;
    const short* p = Kb + (long)bt * 1024 + d0;
    float s[8] = {0.f, 0.f, 0.f, 0.f, 0.f, 0.f, 0.f, 0.f};
    #pragma unroll
    for (int h = 0; h < 16; ++h) {
        s16x8 v = *(const s16x8*)(p + h * 64);
        #pragma unroll
        for (int j = 0; j < 8; ++j) s[j] += b2f(v[j]);
    }
    float4 o0 = {s[0] * 0.0625f, s[1] * 0.0625f, s[2] * 0.0625f, s[3] * 0.0625f};
    float4 o1 = {s[4] * 0.0625f, s[5] * 0.0625f, s[6] * 0.0625f, s[7] * 0.0625f};
    *(float4*)(out + (long)bt * 64 + d0) = o0;
    *(float4*)(out + (long)bt * 64 + d0 + 4) = o1;
}

// ---------------- reduce att_score partials over batch ----------------
__global__ void k_att_reduce(const float* __restrict__ part, float* __restrict__ out,
                             int n, int nb, long stride) {
    int i = blockIdx.x * blockDim.x + threadIdx.x;
    if (i >= n) return;
    float s = 0.f;
    for (int b = 0; b < nb; ++b) s += part[(long)b * stride + i];
    out[i] = s * (1.0f / 256.0f);
}

// ---------------- V transpose: v[B,T,H*64] -> vt[B*H][64][TP] ----------------
__global__ __launch_bounds__(256) void k_vtrans(const short* __restrict__ v, short* __restrict__ vt,
                                                int B, int T, int H, int TP) {
    int b = blockIdx.z, h = blockIdx.y, t0 = blockIdx.x * 64;
    __shared__ short Vs[64][68];
    int tid = threadIdx.x;
    for (int c = tid; c < 512; c += 256) {
        int r = c >> 3, m = c & 7;
        s16x8 val = {0,0,0,0,0,0,0,0};
        if (t0 + r < T) val = *(const s16x8*)(v + ((long)(b * T + t0 + r)) * (H * 64) + h * 64 + m * 8);
        *(s16x8*)&Vs[r][m * 8] = val;
    }
    __syncthreads();
    for (int c = tid; c < 512; c += 256) {
        int d = c >> 3, mw = c & 7;
        s16x8 o;
        #pragma unroll
        for (int j = 0; j < 8; j++) o[j] = Vs[mw * 8 + j][d];
        *(s16x8*)(vt + ((long)((b * H + h) * 64 + d)) * TP + t0 + mw * 8) = o;
    }
}

// ---------------- flash attention: QBLK=128, padded LDS, pre-transposed V ----------------
__global__ __launch_bounds__(256) void k_flash(
    const short* __restrict__ Q, const short* __restrict__ Kb, const short* __restrict__ VT,
    const float* __restrict__ logsz, short* __restrict__ Ctx,
    int B, int T, int E, int H, int SP, int TP, int NTQ) {
    int nwg = gridDim.x;
    int cpx = nwg >> 3;
    int wg = (blockIdx.x & 7) * cpx + (blockIdx.x >> 3);
    int tq = wg % NTQ, h = (wg / NTQ) % H, b = wg / (NTQ * H);
    int t0 = tq * 128;

    __shared__ short Qs[128][68];
    __shared__ short Ks[64][68];
    __shared__ short Vt[64][68];
    __shared__ short Ps[4][32][68];
    __shared__ float Ls[64];
    int tid = threadIdx.x, wid = tid >> 6, lane = tid & 63;
    int lr = lane & 15, lg = lane >> 4;

    for (int c = tid; c < 1024; c += 256) {
        int r = c >> 3, m = c & 7;
        int t = t0 + r; t = t < T ? t : T - 1;
        s16x8 v = *(const s16x8*)(Q + ((long)b * T + t) * E + h * 64 + m * 8);
        *(s16x8*)&Qs[r][m * 8] = v;
    }

    float mreg[2][4], lsum[2][4];
    f32x4 o[2][4];
    #pragma unroll
    for (int i = 0; i < 2; i++)
        #pragma unroll
        for (int q = 0; q < 4; q++) { mreg[i][q] = -INFINITY; lsum[i][q] = 0.f; }
    #pragma unroll
    for (int i = 0; i < 2; i++)
        #pragma unroll
        for (int jd = 0; jd < 4; jd++)
            #pragma unroll
            for (int q = 0; q < 4; q++) o[i][jd][q] = 0.f;

    const short* kb = Kb + (long)b * T * E + h * 64;
    const short* vtb = VT + ((long)(b * H + h)) * 64 * TP;

    for (int s0 = 0; s0 < T; s0 += 64) {
        __syncthreads();
        for (int c = tid; c < 512; c += 256) {
            int r = c >> 3, m = c & 7;
            int s = s0 + r; s = s < T ? s : T - 1;
            *(s16x8*)&Ks[r][m * 8] = *(const s16x8*)(kb + (long)s * E + m * 8);
            *(s16x8*)&Vt[r][m * 8] = *(const s16x8*)(vtb + (long)r * TP + s0 + m * 8);
        }
        if (tid < 64) Ls[tid] = logsz[b * SP + s0 + tid];
        __syncthreads();

        s16x8 kf[2][4];
        #pragma unroll
        for (int ks = 0; ks < 2; ++ks)
            #pragma unroll
            for (int j = 0; j < 4; ++j)
                kf[ks][j] = *(const s16x8*)&Ks[j * 16 + lr][ks * 32 + lg * 8];

        #pragma unroll
        for (int i = 0; i < 2; ++i) {
            f32x4 sf[4];
            #pragma unroll
            for (int j = 0; j < 4; j++)
                #pragma unroll
                for (int q = 0; q < 4; q++) sf[j][q] = 0.f;
            __builtin_amdgcn_s_setprio(1);
            #pragma unroll
            for (int ks = 0; ks < 2; ++ks) {
                s16x8 aq = *(const s16x8*)&Qs[wid * 32 + i * 16 + lr][ks * 32 + lg * 8];
                #pragma unroll
                for (int j = 0; j < 4; j++) sf[j] = MFMA16(aq, kf[ks][j], sf[j]);
            }
            __builtin_amdgcn_s_setprio(0);

            float tmax[4] = {-INFINITY, -INFINITY, -INFINITY, -INFINITY};
            #pragma unroll
            for (int j = 0; j < 4; j++) {
                float bl = Ls[j * 16 + lr];
                #pragma unroll
                for (int q = 0; q < 4; q++) {
                    sf[j][q] += bl;
                    tmax[q] = fmaxf(tmax[q], sf[j][q]);
                }
            }
            #pragma unroll
            for (int q = 0; q < 4; q++)
                #pragma unroll
                for (int msk = 1; msk < 16; msk <<= 1)
                    tmax[q] = fmaxf(tmax[q], __shfl_xor(tmax[q], msk));
            float al[4], rs[4];
            #pragma unroll
            for (int q = 0; q < 4; q++) {
                float mn = fmaxf(mreg[i][q], tmax[q]);
                al[q] = __expf(mreg[i][q] - mn);
                mreg[i][q] = mn;
                rs[q] = 0.f;
            }
            #pragma unroll
            for (int j = 0; j < 4; j++)
                #pragma unroll
                for (int q = 0; q < 4; q++) {
                    float p = __expf(sf[j][q] - mreg[i][q]);
                    sf[j][q] = p;
                    rs[q] += p;
                }
            #pragma unroll
            for (int q = 0; q < 4; q++) {
                #pragma unroll
                for (int msk = 1; msk < 16; msk <<= 1) rs[q] += __shfl_xor(rs[q], msk);
                lsum[i][q] = lsum[i][q] * al[q] + rs[q];
            }
            #pragma unroll
            for (int jd = 0; jd < 4; jd++)
                #pragma unroll
                for (int q = 0; q < 4; q++) o[i][jd][q] *= al[q];

            #pragma unroll
            for (int j = 0; j < 4; j++)
                #pragma unroll
                for (int q = 0; q < 4; q++)
                    Ps[wid][i * 16 + lg * 4 + q][j * 16 + lr] = f2b(sf[j][q]);

            __builtin_amdgcn_s_setprio(1);
            #pragma unroll
            for (int ks = 0; ks < 2; ++ks) {
                s16x8 ap = *(const s16x8*)&Ps[wid][i * 16 + lr][ks * 32 + lg * 8];
                #pragma unroll
                for (int jd = 0; jd < 4; jd++) {
                    s16x8 bv = *(const s16x8*)&Vt[jd * 16 + lr][ks * 32 + lg * 8];
                    o[i][jd] = MFMA16(ap, bv, o[i][jd]);
                }
            }
            __builtin_amdgcn_s_setprio(0);
        }
    }

    short* cb = Ctx + ((long)b * T + t0) * E + h * 64;
    #pragma unroll
    for (int i = 0; i < 2; i++)
        #pragma unroll
        for (int q = 0; q < 4; q++) {
            int t = wid * 32 + i * 16 + lg * 4 + q;
            if (t0 + t >= T) continue;
            float inv = 1.f / lsum[i][q];
            #pragma unroll
            for (int jd = 0; jd < 4; jd++)
                cb[(long)t * E + jd * 16 + lr] = f2b(o[i][jd][q] * inv);
        }
}

extern "C" void kernel_launch(void* const* d_in, const int* in_sizes, int n_in,
                              void* d_out, int out_size, void* d_ws, size_t ws_size,
                              hipStream_t stream) {
    (void)in_sizes; (void)n_in; (void)out_size; (void)ws_size;
    const int B = 16, T = 577, E = 1024, H = 16;
    const int SP = 640, TP = 640;
    const float* hs   = (const float*)d_in[0];
    const float* size = (const float*)d_in[1];
    const float* wq   = (const float*)d_in[2];
    const float* bq   = (const float*)d_in[3];
    const float* wk   = (const float*)d_in[4];
    const float* bk   = (const float*)d_in[5];
    const float* wv   = (const float*)d_in[6];
    const float* bv   = (const float*)d_in[7];
    const float* wo   = (const float*)d_in[8];
    const float* bo   = (const float*)d_in[9];

    float* out_attn = (float*)d_out;                  // B*T*E
    float* out_mk   = out_attn + (long)B * T * E;     // B*T*D
    float* out_as   = out_mk + (long)B * T * 64;      // T*T

    long nBTE = (long)B * T * E;
    long nEE  = (long)E * E;
    char* ws = (char*)d_ws;
    short* hs_b  = (short*)ws; ws += nBTE * 2;
    short* wq_b  = (short*)ws; ws += nEE * 2;   // wq|wk|wv contiguous -> [3072][1024]
    short* wk_b  = (short*)ws; ws += nEE * 2;
    short* wv_b  = (short*)ws; ws += nEE * 2;
    short* wo_b  = (short*)ws; ws += nEE * 2;
    short* q_b   = (short*)ws; ws += nBTE * 2;
    short* k_b   = (short*)ws; ws += nBTE * 2;
    short* v_b   = (short*)ws; ws += nBTE * 2;
    short* ctx_b = (short*)ws; ws += nBTE * 2;
    float* logsz = (float*)ws; ws += (long)B * SP * 4;
    float* att_p = (float*)ws; ws += (long)B * T * T * 4;
    short* vt = (short*)att_p;   // aliases att_p, written after reduce consumed it

    k_f32_to_bf16<<<2048, 256, 0, stream>>>(hs, hs_b, nBTE);
    k_f32_to_bf16<<<1024, 256, 0, stream>>>(wq, wq_b, nEE);
    k_f32_to_bf16<<<1024, 256, 0, stream>>>(wk, wk_b, nEE);
    k_f32_to_bf16<<<1024, 256, 0, stream>>>(wv, wv_b, nEE);
    k_f32_to_bf16<<<1024, 256, 0, stream>>>(wo, wo_b, nEE);
    k_logsize<<<(B * SP + 255) / 256, 256, 0, stream>>>(size, logsz, B, T, SP);

    int M = B * T;  // 9232
    // fused QKV: A=[M][1024], B=[3072][1024] (wq|wk|wv), routed epilogue
    {
        int Mtiles = (M + 255) / 256, Ntiles = 3072 / 256;
        k_gemm8<true><<<Mtiles * Ntiles, 512, 0, stream>>>(
            hs_b, wq_b, bq, bk, bv, q_b, k_b, v_b, nullptr, M, 3072, E, Ntiles);
    }

    // att_score partials + deterministic reduce (old 128^2 core)
    dim3 g_att((T + 127) / 128, (T + 127) / 128, B);
    k_att<<<g_att, dim3(256), 0, stream>>>(q_b, k_b, att_p, T, E);
    k_att_reduce<<<((T * T) + 255) / 256, 256, 0, stream>>>(att_p, out_as, T * T, B, (long)T * T);

    dim3 g_vt((T + 63) / 64, H, B);
    k_vtrans<<<g_vt, dim3(256), 0, stream>>>(v_b, vt, B, T, H, TP);

    k_mean_keys8<<<((B * T * 8) + 255) / 256, 256, 0, stream>>>(k_b, out_mk, B * T);

    const int NTQ = (T + 127) / 128;
    int nfl = NTQ * H * B;
    k_flash<<<nfl, dim3(256), 0, stream>>>(q_b, k_b, vt, logsz, ctx_b, B, T, E, H, SP, TP, NTQ);

    // output projection -> fp32 d_out (8-phase core, no routing)
    {
        int Mtiles = (M + 255) / 256, Ntiles = 1024 / 256;
        k_gemm8<false><<<Mtiles * Ntiles, 512, 0, stream>>>(
            ctx_b, wo_b, bo, nullptr, nullptr, nullptr, nullptr, nullptr,
            out_attn, M, 1024, E, Ntiles);
    }
}

// Round 5
// 339.681 us; speedup vs baseline: 4.3363x; 1.0790x over previous
//
#include <hip/hip_runtime.h>
#include <hip/hip_bf16.h>
#include <math.h>

typedef __attribute__((ext_vector_type(8))) short s16x8;
typedef __attribute__((ext_vector_type(4))) short s16x4;
typedef __attribute__((ext_vector_type(4))) float f32x4;
typedef __attribute__((ext_vector_type(8))) __bf16 bf16x8;

#define MFMA16(a, b, c) __builtin_amdgcn_mfma_f32_16x16x32_bf16( \
    __builtin_bit_cast(bf16x8, (a)), __builtin_bit_cast(bf16x8, (b)), (c), 0, 0, 0)

__device__ __forceinline__ short f2b(float f) {
    union { float f; unsigned u; } x; x.f = f;
    unsigned u = x.u;
    unsigned r = (u + 0x7FFFu + ((u >> 16) & 1u)) >> 16;
    return (short)r;
}
__device__ __forceinline__ float b2f(short b) {
    union { unsigned u; float f; } x;
    x.u = ((unsigned)(unsigned short)b) << 16;
    return x.f;
}

__device__ __forceinline__ void gload16(const void* g, void* l) {
    __builtin_amdgcn_global_load_lds(
        (const __attribute__((address_space(1))) unsigned int*)g,
        (__attribute__((address_space(3))) unsigned int*)l, 16, 0, 0);
}

// ---------------- fp32 -> bf16 convert ----------------
__global__ void k_f32_to_bf16(const float* __restrict__ in, short* __restrict__ out, long n) {
    long i = ((long)blockIdx.x * blockDim.x + threadIdx.x) * 4;
    long stride = (long)gridDim.x * blockDim.x * 4;
    for (; i < n; i += stride) {
        float4 v = *(const float4*)(in + i);
        s16x4 o = { f2b(v.x), f2b(v.y), f2b(v.z), f2b(v.w) };
        *(s16x4*)(out + i) = o;
    }
}

// ---------------- log2(size) with padding (exp2-domain softmax) ----------------
__global__ void k_logsize(const float* __restrict__ size, float* __restrict__ out,
                          int B, int T, int SP) {
    int i = blockIdx.x * blockDim.x + threadIdx.x;
    if (i >= B * SP) return;
    int b = i / SP, s = i % SP;
    out[i] = (s < T) ? log2f(size[b * T + s]) : -1e30f;
}

// ================= 256x256 8-wave phase-pipelined GEMM (C = A @ B^T) =================
__device__ __forceinline__ void stage_half(const short* __restrict__ src, int ldk,
                                           int row0, int maxrow, int k0,
                                           short* lds, int tid) {
    #pragma unroll
    for (int j = 0; j < 2; ++j) {
        int ch = tid + j * 512;
        int r = ch >> 3;
        int cby = ((ch & 7) * 16) ^ ((r & 7) << 4);
        int gr = row0 + r; gr = gr < maxrow ? gr : maxrow - 1;
        gload16((const char*)(src + (long)gr * ldk + k0) + cby,
                (char*)lds + ch * 16);
    }
}

__device__ __forceinline__ s16x8 lds_frag(const short* half, int r, int ks, int lg) {
    int cby = ((ks << 6) + (lg << 4)) ^ ((r & 7) << 4);
    return *(const s16x8*)((const char*)half + r * 128 + cby);
}

template<bool ROUTE>
__global__ __launch_bounds__(512, 2) void k_gemm8(
    const short* __restrict__ A, const short* __restrict__ Bw,
    const float* __restrict__ bb0, const float* __restrict__ bb1, const float* __restrict__ bb2,
    short* __restrict__ o0, short* __restrict__ o1, short* __restrict__ o2,
    float* __restrict__ Cf, int M, int N, int K, int Ntiles, float alpha0) {

    __shared__ short AS[2][2][128 * 64];
    __shared__ short BS[2][2][128 * 64];

    int nwg = gridDim.x, orig = blockIdx.x;
    int qq = nwg >> 3, rr = nwg & 7;
    int xcd = orig & 7, pos = orig >> 3;
    int wg = (xcd < rr ? xcd * (qq + 1) : rr * (qq + 1) + (xcd - rr) * qq) + pos;
    int bx = wg % Ntiles, by = wg / Ntiles;
    int row0 = by * 256, col0 = bx * 256;

    int tid = threadIdx.x;
    int lane = tid & 63, wave = tid >> 6;
    int wm = wave >> 2, wn = wave & 3;
    int lr = lane & 15, lg = lane >> 4;
    int bh = wn >> 1, brb = (wn & 1) * 64;

    f32x4 acc[8][4];
    #pragma unroll
    for (int i = 0; i < 8; i++)
        #pragma unroll
        for (int j = 0; j < 4; j++)
            #pragma unroll
            for (int q = 0; q < 4; q++) acc[i][j][q] = 0.f;

    int nt = K >> 6;
    stage_half(A,  K, row0,       M, 0, AS[0][0], tid);
    stage_half(A,  K, row0 + 128, M, 0, AS[0][1], tid);
    stage_half(Bw, K, col0,       N, 0, BS[0][0], tid);
    stage_half(Bw, K, col0 + 128, N, 0, BS[0][1], tid);

    for (int t = 0; t < nt; ++t) {
        int cur = t & 1;
        asm volatile("s_waitcnt vmcnt(0)" ::: "memory");
        __builtin_amdgcn_s_barrier();
        const short* Ah = AS[cur][wm];
        const short* Bh = BS[cur][bh];
        s16x8 bf[4][2];
        #pragma unroll
        for (int p = 0; p < 4; ++p) {
            if (t + 1 < nt) {
                int k1 = (t + 1) << 6;
                if (p == 0) {
                    stage_half(A, K, row0,       M, k1, AS[cur ^ 1][0], tid);
                    stage_half(A, K, row0 + 128, M, k1, AS[cur ^ 1][1], tid);
                } else if (p == 1) {
                    stage_half(Bw, K, col0,       N, k1, BS[cur ^ 1][0], tid);
                    stage_half(Bw, K, col0 + 128, N, k1, BS[cur ^ 1][1], tid);
                }
            }
            if (p == 0) {
                #pragma unroll
                for (int nf = 0; nf < 4; ++nf)
                    #pragma unroll
                    for (int ks = 0; ks < 2; ++ks)
                        bf[nf][ks] = lds_frag(Bh, brb + nf * 16 + lr, ks, lg);
            }
            s16x8 af[2][2];
            #pragma unroll
            for (int i = 0; i < 2; ++i)
                #pragma unroll
                for (int ks = 0; ks < 2; ++ks)
                    af[i][ks] = lds_frag(Ah, (2 * p + i) * 16 + lr, ks, lg);
            __builtin_amdgcn_s_setprio(1);
            #pragma unroll
            for (int i = 0; i < 2; ++i)
                #pragma unroll
                for (int nf = 0; nf < 4; ++nf)
                    #pragma unroll
                    for (int ks = 0; ks < 2; ++ks)
                        acc[2 * p + i][nf] = MFMA16(af[i][ks], bf[nf][ks], acc[2 * p + i][nf]);
            __builtin_amdgcn_s_setprio(0);
            __builtin_amdgcn_s_barrier();
        }
    }

    int wrow = row0 + wm * 128;
    #pragma unroll
    for (int mf = 0; mf < 8; ++mf) {
        int grow = wrow + mf * 16 + lg * 4;
        #pragma unroll
        for (int nf = 0; nf < 4; ++nf) {
            int gc = col0 + wn * 64 + nf * 16 + lr;
            if (gc >= N) continue;
            if (ROUTE) {
                int which = gc >> 10, lc = gc & 1023;
                float bias = (which == 0 ? bb0 : which == 1 ? bb1 : bb2)[lc];
                float alpha = (which == 0) ? alpha0 : 1.0f;
                short* op = (which == 0 ? o0 : which == 1 ? o1 : o2);
                #pragma unroll
                for (int q = 0; q < 4; ++q) {
                    int r2 = grow + q;
                    if (r2 < M) op[(long)r2 * 1024 + lc] = f2b((acc[mf][nf][q] + bias) * alpha);
                }
            } else {
                float bias = bb0[gc];
                #pragma unroll
                for (int q = 0; q < 4; ++q) {
                    int r2 = grow + q;
                    if (r2 < M) Cf[(long)r2 * N + gc] = acc[mf][nf][q] + bias;
                }
            }
        }
    }
}

// ---------------- 128^2 core for att partials ----------------
__device__ __forceinline__ void gemm_core(
    const short* __restrict__ Ab, const short* __restrict__ Bb,
    float* __restrict__ Cf, int M, int N, int K, int ldc, int row0, int col0) {
    __shared__ short As[128 * 64];
    __shared__ short Bs[128 * 64];
    int tid = threadIdx.x;
    int lane = tid & 63, wave = tid >> 6;
    int wr = wave >> 1, wc = wave & 1;
    int lr = lane & 15, lg = lane >> 4;
    f32x4 acc[4][4];
    #pragma unroll
    for (int i = 0; i < 4; i++)
        #pragma unroll
        for (int j = 0; j < 4; j++)
            #pragma unroll
            for (int q = 0; q < 4; q++) acc[i][j][q] = 0.f;

    for (int k0 = 0; k0 < K; k0 += 64) {
        __syncthreads();
        #pragma unroll
        for (int i = 0; i < 4; ++i) {
            int cw = i * 256 + wave * 64;
            int c = cw + lane;
            int r = c >> 3;
            int cs = (c & 7) * 8;
            int ra = row0 + r; ra = ra < M ? ra : M - 1;
            gload16(Ab + (long)ra * K + k0 + cs, &As[cw * 8]);
            int rb = col0 + r; rb = rb < N ? rb : N - 1;
            gload16(Bb + (long)rb * K + k0 + cs, &Bs[cw * 8]);
        }
        __syncthreads();
        #pragma unroll
        for (int ks = 0; ks < 2; ++ks) {
            s16x8 af[4], bfr[4];
            #pragma unroll
            for (int i = 0; i < 4; ++i)
                af[i] = *(const s16x8*)&As[(wr * 64 + i * 16 + lr) * 64 + ks * 32 + lg * 8];
            #pragma unroll
            for (int j = 0; j < 4; ++j)
                bfr[j] = *(const s16x8*)&Bs[(wc * 64 + j * 16 + lr) * 64 + ks * 32 + lg * 8];
            #pragma unroll
            for (int i = 0; i < 4; ++i)
                #pragma unroll
                for (int j = 0; j < 4; ++j)
                    acc[i][j] = MFMA16(af[i], bfr[j], acc[i][j]);
        }
    }
    #pragma unroll
    for (int i = 0; i < 4; i++) {
        int rbase = row0 + wr * 64 + i * 16 + lg * 4;
        #pragma unroll
        for (int j = 0; j < 4; j++) {
            int c = col0 + wc * 64 + j * 16 + lr;
            if (c >= N) continue;
            #pragma unroll
            for (int q = 0; q < 4; q++) {
                int r = rbase + q;
                if (r >= M) continue;
                Cf[(long)r * ldc + c] = acc[i][j][q];
            }
        }
    }
}

__global__ __launch_bounds__(256) void k_att(
    const short* __restrict__ q, const short* __restrict__ k,
    float* __restrict__ attp, int T, int E) {
    int z = blockIdx.z;
    gemm_core(q + (long)z * T * E, k + (long)z * T * E,
              attp + (long)z * T * T, T, T, E, T,
              blockIdx.y * 128, blockIdx.x * 128);
}

// ---------------- mean over heads of K ----------------
__global__ void k_mean_keys8(const short* __restrict__ Kb, float* __restrict__ out, int BT) {
    int i = blockIdx.x * blockDim.x + threadIdx.x;
    if (i >= BT * 8) return;
    int bt = i >> 3, d0 = (i & 7) * 8;
    const short* p = Kb + (long)bt * 1024 + d0;
    float s[8] = {0.f, 0.f, 0.f, 0.f, 0.f, 0.f, 0.f, 0.f};
    #pragma unroll
    for (int h = 0; h < 16; ++h) {
        s16x8 v = *(const s16x8*)(p + h * 64);
        #pragma unroll
        for (int j = 0; j < 8; ++j) s[j] += b2f(v[j]);
    }
    float4 o0 = {s[0] * 0.0625f, s[1] * 0.0625f, s[2] * 0.0625f, s[3] * 0.0625f};
    float4 o1 = {s[4] * 0.0625f, s[5] * 0.0625f, s[6] * 0.0625f, s[7] * 0.0625f};
    *(float4*)(out + (long)bt * 64 + d0) = o0;
    *(float4*)(out + (long)bt * 64 + d0 + 4) = o1;
}

// ---------------- reduce att_score partials over batch ----------------
// scale = ln2/256 compensates the log2e folded into q
__global__ void k_att_reduce(const float* __restrict__ part, float* __restrict__ out,
                             int n, int nb, long stride) {
    int i = blockIdx.x * blockDim.x + threadIdx.x;
    if (i >= n) return;
    float s = 0.f;
    for (int b = 0; b < nb; ++b) s += part[(long)b * stride + i];
    out[i] = s * 0.002707606174062286f;  // ln(2)/256
}

// ---------------- V transpose: v[B,T,H*64] -> vt[B*H][64][TP] ----------------
__global__ __launch_bounds__(256) void k_vtrans(const short* __restrict__ v, short* __restrict__ vt,
                                                int B, int T, int H, int TP) {
    int b = blockIdx.z, h = blockIdx.y, t0 = blockIdx.x * 64;
    __shared__ short Vs[64][68];
    int tid = threadIdx.x;
    for (int c = tid; c < 512; c += 256) {
        int r = c >> 3, m = c & 7;
        s16x8 val = {0,0,0,0,0,0,0,0};
        if (t0 + r < T) val = *(const s16x8*)(v + ((long)(b * T + t0 + r)) * (H * 64) + h * 64 + m * 8);
        *(s16x8*)&Vs[r][m * 8] = val;
    }
    __syncthreads();
    for (int c = tid; c < 512; c += 256) {
        int d = c >> 3, mw = c & 7;
        s16x8 o;
        #pragma unroll
        for (int j = 0; j < 8; j++) o[j] = Vs[mw * 8 + j][d];
        *(s16x8*)(vt + ((long)((b * H + h) * 64 + d)) * TP + t0 + mw * 8) = o;
    }
}

// ---------------- flash attention v3: exp2 softmax, defer-max, Q-in-reg, async stage ----------------
__global__ __launch_bounds__(256) void k_flash(
    const short* __restrict__ Q, const short* __restrict__ Kb, const short* __restrict__ VT,
    const float* __restrict__ logsz, short* __restrict__ Ctx,
    int B, int T, int E, int H, int SP, int TP, int NTQ) {
    int nwg = gridDim.x;
    int cpx = nwg >> 3;
    int wg = (blockIdx.x & 7) * cpx + (blockIdx.x >> 3);
    int tq = wg % NTQ, h = (wg / NTQ) % H, b = wg / (NTQ * H);
    int t0 = tq * 128;

    __shared__ short Ks[64][68];
    __shared__ short Vt[64][68];
    __shared__ short Ps[4][32][68];
    __shared__ float Ls[64];
    int tid = threadIdx.x, wid = tid >> 6, lane = tid & 63;
    int lr = lane & 15, lg = lane >> 4;

    // Q fragments directly from global (once per block)
    s16x8 aqf[2][2];
    #pragma unroll
    for (int i = 0; i < 2; ++i) {
        int t = t0 + wid * 32 + i * 16 + lr; t = t < T ? t : T - 1;
        #pragma unroll
        for (int ks = 0; ks < 2; ++ks)
            aqf[i][ks] = *(const s16x8*)(Q + ((long)b * T + t) * E + h * 64 + ks * 32 + lg * 8);
    }

    const short* kb  = Kb + (long)b * T * E + h * 64;
    const short* vtb = VT + ((long)(b * H + h)) * 64 * TP;

    int c0 = tid, c1 = tid + 256;
    int r0 = c0 >> 3, m0 = c0 & 7, r1 = c1 >> 3, m1 = c1 & 7;
    s16x8 kreg0, kreg1, vreg0, vreg1;
    float lreg = 0.f;

    // fetch tile s0 into registers
    {
        int s = r0; s = s < T ? s : T - 1;
        kreg0 = *(const s16x8*)(kb + (long)s * E + m0 * 8);
        s = r1; s = s < T ? s : T - 1;
        kreg1 = *(const s16x8*)(kb + (long)s * E + m1 * 8);
        vreg0 = *(const s16x8*)(vtb + (long)r0 * TP + 0 + m0 * 8);
        vreg1 = *(const s16x8*)(vtb + (long)r1 * TP + 0 + m1 * 8);
        if (tid < 64) lreg = logsz[b * SP + 0 + tid];
    }

    float mreg[2][4], lsum[2][4];
    f32x4 o[2][4];
    #pragma unroll
    for (int i = 0; i < 2; i++)
        #pragma unroll
        for (int q = 0; q < 4; q++) { mreg[i][q] = -INFINITY; lsum[i][q] = 0.f; }
    #pragma unroll
    for (int i = 0; i < 2; i++)
        #pragma unroll
        for (int jd = 0; jd < 4; jd++)
            #pragma unroll
            for (int q = 0; q < 4; q++) o[i][jd][q] = 0.f;

    for (int s0 = 0; s0 < T; s0 += 64) {
        // write staged regs into LDS
        *(s16x8*)&Ks[r0][m0 * 8] = kreg0;
        *(s16x8*)&Ks[r1][m1 * 8] = kreg1;
        *(s16x8*)&Vt[r0][m0 * 8] = vreg0;
        *(s16x8*)&Vt[r1][m1 * 8] = vreg1;
        if (tid < 64) Ls[tid] = lreg;
        __syncthreads();

        // async fetch next tile (hidden under compute)
        if (s0 + 64 < T) {
            int sn = s0 + 64;
            int s = sn + r0; s = s < T ? s : T - 1;
            kreg0 = *(const s16x8*)(kb + (long)s * E + m0 * 8);
            s = sn + r1; s = s < T ? s : T - 1;
            kreg1 = *(const s16x8*)(kb + (long)s * E + m1 * 8);
            vreg0 = *(const s16x8*)(vtb + (long)r0 * TP + sn + m0 * 8);
            vreg1 = *(const s16x8*)(vtb + (long)r1 * TP + sn + m1 * 8);
            if (tid < 64) lreg = logsz[b * SP + sn + tid];
        }

        float bl[4];
        #pragma unroll
        for (int j = 0; j < 4; j++) bl[j] = Ls[j * 16 + lr];

        s16x8 kf[2][4];
        #pragma unroll
        for (int ks = 0; ks < 2; ++ks)
            #pragma unroll
            for (int j = 0; j < 4; ++j)
                kf[ks][j] = *(const s16x8*)&Ks[j * 16 + lr][ks * 32 + lg * 8];

        #pragma unroll
        for (int i = 0; i < 2; ++i) {
            f32x4 sf[4];
            #pragma unroll
            for (int j = 0; j < 4; j++)
                #pragma unroll
                for (int q = 0; q < 4; q++) sf[j][q] = 0.f;
            __builtin_amdgcn_s_setprio(1);
            #pragma unroll
            for (int ks = 0; ks < 2; ++ks)
                #pragma unroll
                for (int j = 0; j < 4; j++) sf[j] = MFMA16(aqf[i][ks], kf[ks][j], sf[j]);
            __builtin_amdgcn_s_setprio(0);

            // bias add + lane-local max
            float tmax[4];
            #pragma unroll
            for (int q = 0; q < 4; q++) {
                sf[0][q] += bl[0]; sf[1][q] += bl[1];
                sf[2][q] += bl[2]; sf[3][q] += bl[3];
                tmax[q] = fmaxf(fmaxf(sf[0][q], sf[1][q]), fmaxf(sf[2][q], sf[3][q]));
            }
            // defer-max: full reduce + rescale only when max grew past threshold
            int ok = 1;
            #pragma unroll
            for (int q = 0; q < 4; q++) ok &= (tmax[q] <= mreg[i][q] + 11.0f) ? 1 : 0;
            if (!__all(ok)) {
                #pragma unroll
                for (int q = 0; q < 4; q++) {
                    #pragma unroll
                    for (int msk = 1; msk < 16; msk <<= 1)
                        tmax[q] = fmaxf(tmax[q], __shfl_xor(tmax[q], msk));
                    float mn = fmaxf(mreg[i][q], tmax[q]);
                    float al = exp2f(mreg[i][q] - mn);
                    mreg[i][q] = mn;
                    lsum[i][q] *= al;
                    #pragma unroll
                    for (int jd = 0; jd < 4; jd++) o[i][jd][q] *= al;
                }
            }
            float rs[4] = {0.f, 0.f, 0.f, 0.f};
            #pragma unroll
            for (int j = 0; j < 4; j++)
                #pragma unroll
                for (int q = 0; q < 4; q++) {
                    float p = exp2f(sf[j][q] - mreg[i][q]);
                    sf[j][q] = p;
                    rs[q] += p;
                }
            #pragma unroll
            for (int q = 0; q < 4; q++) {
                #pragma unroll
                for (int msk = 1; msk < 16; msk <<= 1) rs[q] += __shfl_xor(rs[q], msk);
                lsum[i][q] += rs[q];
            }
            #pragma unroll
            for (int j = 0; j < 4; j++)
                #pragma unroll
                for (int q = 0; q < 4; q++)
                    Ps[wid][i * 16 + lg * 4 + q][j * 16 + lr] = f2b(sf[j][q]);

            __builtin_amdgcn_s_setprio(1);
            #pragma unroll
            for (int ks = 0; ks < 2; ++ks) {
                s16x8 ap = *(const s16x8*)&Ps[wid][i * 16 + lr][ks * 32 + lg * 8];
                #pragma unroll
                for (int jd = 0; jd < 4; jd++) {
                    s16x8 bv = *(const s16x8*)&Vt[jd * 16 + lr][ks * 32 + lg * 8];
                    o[i][jd] = MFMA16(ap, bv, o[i][jd]);
                }
            }
            __builtin_amdgcn_s_setprio(0);
        }
        __syncthreads();
    }

    short* cb = Ctx + ((long)b * T + t0) * E + h * 64;
    #pragma unroll
    for (int i = 0; i < 2; i++)
        #pragma unroll
        for (int q = 0; q < 4; q++) {
            int t = wid * 32 + i * 16 + lg * 4 + q;
            if (t0 + t >= T) continue;
            float inv = 1.f / lsum[i][q];
            #pragma unroll
            for (int jd = 0; jd < 4; jd++)
                cb[(long)t * E + jd * 16 + lr] = f2b(o[i][jd][q] * inv);
        }
}

extern "C" void kernel_launch(void* const* d_in, const int* in_sizes, int n_in,
                              void* d_out, int out_size, void* d_ws, size_t ws_size,
                              hipStream_t stream) {
    (void)in_sizes; (void)n_in; (void)out_size; (void)ws_size;
    const int B = 16, T = 577, E = 1024, H = 16;
    const int SP = 640, TP = 640;
    const float* hs   = (const float*)d_in[0];
    const float* size = (const float*)d_in[1];
    const float* wq   = (const float*)d_in[2];
    const float* bq   = (const float*)d_in[3];
    const float* wk   = (const float*)d_in[4];
    const float* bk   = (const float*)d_in[5];
    const float* wv   = (const float*)d_in[6];
    const float* bv   = (const float*)d_in[7];
    const float* wo   = (const float*)d_in[8];
    const float* bo   = (const float*)d_in[9];

    float* out_attn = (float*)d_out;                  // B*T*E
    float* out_mk   = out_attn + (long)B * T * E;     // B*T*D
    float* out_as   = out_mk + (long)B * T * 64;      // T*T

    long nBTE = (long)B * T * E;
    long nEE  = (long)E * E;
    char* ws = (char*)d_ws;
    short* hs_b  = (short*)ws; ws += nBTE * 2;
    short* wq_b  = (short*)ws; ws += nEE * 2;   // wq|wk|wv contiguous -> [3072][1024]
    short* wk_b  = (short*)ws; ws += nEE * 2;
    short* wv_b  = (short*)ws; ws += nEE * 2;
    short* wo_b  = (short*)ws; ws += nEE * 2;
    short* q_b   = (short*)ws; ws += nBTE * 2;
    short* k_b   = (short*)ws; ws += nBTE * 2;
    short* v_b   = (short*)ws; ws += nBTE * 2;
    short* ctx_b = (short*)ws; ws += nBTE * 2;
    float* logsz = (float*)ws; ws += (long)B * SP * 4;
    float* att_p = (float*)ws; ws += (long)B * T * T * 4;
    short* vt = (short*)att_p;   // aliases att_p, written after reduce consumed it

    k_f32_to_bf16<<<2048, 256, 0, stream>>>(hs, hs_b, nBTE);
    k_f32_to_bf16<<<1024, 256, 0, stream>>>(wq, wq_b, nEE);
    k_f32_to_bf16<<<1024, 256, 0, stream>>>(wk, wk_b, nEE);
    k_f32_to_bf16<<<1024, 256, 0, stream>>>(wv, wv_b, nEE);
    k_f32_to_bf16<<<1024, 256, 0, stream>>>(wo, wo_b, nEE);
    k_logsize<<<(B * SP + 255) / 256, 256, 0, stream>>>(size, logsz, B, T, SP);

    int M = B * T;  // 9232
    // fused QKV; q carries 0.125*log2(e) for exp2-domain softmax (compensated in att_reduce)
    {
        int Mtiles = (M + 255) / 256, Ntiles = 3072 / 256;
        k_gemm8<true><<<Mtiles * Ntiles, 512, 0, stream>>>(
            hs_b, wq_b, bq, bk, bv, q_b, k_b, v_b, nullptr, M, 3072, E, Ntiles,
            0.18033688011112042f);  // 0.125 * log2(e)
    }

    dim3 g_att((T + 127) / 128, (T + 127) / 128, B);
    k_att<<<g_att, dim3(256), 0, stream>>>(q_b, k_b, att_p, T, E);
    k_att_reduce<<<((T * T) + 255) / 256, 256, 0, stream>>>(att_p, out_as, T * T, B, (long)T * T);

    dim3 g_vt((T + 63) / 64, H, B);
    k_vtrans<<<g_vt, dim3(256), 0, stream>>>(v_b, vt, B, T, H, TP);

    k_mean_keys8<<<((B * T * 8) + 255) / 256, 256, 0, stream>>>(k_b, out_mk, B * T);

    const int NTQ = (T + 127) / 128;
    int nfl = NTQ * H * B;
    k_flash<<<nfl, dim3(256), 0, stream>>>(q_b, k_b, vt, logsz, ctx_b, B, T, E, H, SP, TP, NTQ);

    {
        int Mtiles = (M + 255) / 256, Ntiles = 1024 / 256;
        k_gemm8<false><<<Mtiles * Ntiles, 512, 0, stream>>>(
            ctx_b, wo_b, bo, nullptr, nullptr, nullptr, nullptr, nullptr,
            out_attn, M, 1024, E, Ntiles, 1.0f);
    }
}

// Round 6
// 311.500 us; speedup vs baseline: 4.7287x; 1.0905x over previous
//
#include <hip/hip_runtime.h>
#include <hip/hip_bf16.h>
#include <math.h>

typedef __attribute__((ext_vector_type(8))) short s16x8;
typedef __attribute__((ext_vector_type(4))) short s16x4;
typedef __attribute__((ext_vector_type(4))) float f32x4;
typedef __attribute__((ext_vector_type(8))) __bf16 bf16x8;

#define MFMA16(a, b, c) __builtin_amdgcn_mfma_f32_16x16x32_bf16( \
    __builtin_bit_cast(bf16x8, (a)), __builtin_bit_cast(bf16x8, (b)), (c), 0, 0, 0)

__device__ __forceinline__ short f2b(float f) {
    union { float f; unsigned u; } x; x.f = f;
    unsigned u = x.u;
    unsigned r = (u + 0x7FFFu + ((u >> 16) & 1u)) >> 16;
    return (short)r;
}
__device__ __forceinline__ float b2f(short b) {
    union { unsigned u; float f; } x;
    x.u = ((unsigned)(unsigned short)b) << 16;
    return x.f;
}

__device__ __forceinline__ void gload16(const void* g, void* l) {
    __builtin_amdgcn_global_load_lds(
        (const __attribute__((address_space(1))) unsigned int*)g,
        (__attribute__((address_space(3))) unsigned int*)l, 16, 0, 0);
}

// ---------------- fp32 -> bf16 convert ----------------
__global__ void k_f32_to_bf16(const float* __restrict__ in, short* __restrict__ out, long n) {
    long i = ((long)blockIdx.x * blockDim.x + threadIdx.x) * 4;
    long stride = (long)gridDim.x * blockDim.x * 4;
    for (; i < n; i += stride) {
        float4 v = *(const float4*)(in + i);
        s16x4 o = { f2b(v.x), f2b(v.y), f2b(v.z), f2b(v.w) };
        *(s16x4*)(out + i) = o;
    }
}

// ---------------- raw size with 0-padding (softmax weight; size in [1,2)) ----------------
__global__ void k_sizepad(const float* __restrict__ size, float* __restrict__ out,
                          int B, int T, int SP) {
    int i = blockIdx.x * blockDim.x + threadIdx.x;
    if (i >= B * SP) return;
    int b = i / SP, s = i % SP;
    out[i] = (s < T) ? size[b * T + s] : 0.f;
}

// ================= 256x256 8-wave double-buffered GEMM, 1 barrier/K-tile =================
__device__ __forceinline__ void stage_half(const short* __restrict__ src, int ldk,
                                           int row0, int maxrow, int k0,
                                           short* lds, int tid) {
    #pragma unroll
    for (int j = 0; j < 2; ++j) {
        int ch = tid + j * 512;
        int r = ch >> 3;
        int cby = ((ch & 7) * 16) ^ ((r & 7) << 4);
        int gr = row0 + r; gr = gr < maxrow ? gr : maxrow - 1;
        gload16((const char*)(src + (long)gr * ldk + k0) + cby,
                (char*)lds + ch * 16);
    }
}

__device__ __forceinline__ s16x8 lds_frag(const short* half, int r, int ks, int lg) {
    int cby = ((ks << 6) + (lg << 4)) ^ ((r & 7) << 4);
    return *(const s16x8*)((const char*)half + r * 128 + cby);
}

template<bool ROUTE>
__global__ __launch_bounds__(512, 2) void k_gemm8(
    const short* __restrict__ A, const short* __restrict__ Bw,
    const float* __restrict__ bb0, const float* __restrict__ bb1, const float* __restrict__ bb2,
    short* __restrict__ o0, short* __restrict__ o1, short* __restrict__ o2,
    float* __restrict__ Cf, int M, int N, int K, int Ntiles, float alpha0) {

    __shared__ short AS[2][2][128 * 64];
    __shared__ short BS[2][2][128 * 64];

    int nwg = gridDim.x, orig = blockIdx.x;
    int qq = nwg >> 3, rr = nwg & 7;
    int xcd = orig & 7, pos = orig >> 3;
    int wg = (xcd < rr ? xcd * (qq + 1) : rr * (qq + 1) + (xcd - rr) * qq) + pos;
    int bx = wg % Ntiles, by = wg / Ntiles;
    int row0 = by * 256, col0 = bx * 256;

    int tid = threadIdx.x;
    int lane = tid & 63, wave = tid >> 6;
    int wm = wave >> 2, wn = wave & 3;
    int lr = lane & 15, lg = lane >> 4;
    int bh = wn >> 1, brb = (wn & 1) * 64;

    f32x4 acc[8][4];
    #pragma unroll
    for (int i = 0; i < 8; i++)
        #pragma unroll
        for (int j = 0; j < 4; j++)
            #pragma unroll
            for (int q = 0; q < 4; q++) acc[i][j][q] = 0.f;

    int nt = K >> 6;
    stage_half(A,  K, row0,       M, 0, AS[0][0], tid);
    stage_half(A,  K, row0 + 128, M, 0, AS[0][1], tid);
    stage_half(Bw, K, col0,       N, 0, BS[0][0], tid);
    stage_half(Bw, K, col0 + 128, N, 0, BS[0][1], tid);

    for (int t = 0; t < nt; ++t) {
        int cur = t & 1;
        asm volatile("s_waitcnt vmcnt(0)" ::: "memory");  // own stages landed
        __builtin_amdgcn_s_barrier();                      // all waves' stages + prev reads done
        if (t + 1 < nt) {                                  // prefetch next tile (in flight all tile)
            int k1 = (t + 1) << 6;
            stage_half(A,  K, row0,       M, k1, AS[cur ^ 1][0], tid);
            stage_half(A,  K, row0 + 128, M, k1, AS[cur ^ 1][1], tid);
            stage_half(Bw, K, col0,       N, k1, BS[cur ^ 1][0], tid);
            stage_half(Bw, K, col0 + 128, N, k1, BS[cur ^ 1][1], tid);
        }
        const short* Ah = AS[cur][wm];
        const short* Bh = BS[cur][bh];
        s16x8 bf[4][2];
        #pragma unroll
        for (int nf = 0; nf < 4; ++nf)
            #pragma unroll
            for (int ks = 0; ks < 2; ++ks)
                bf[nf][ks] = lds_frag(Bh, brb + nf * 16 + lr, ks, lg);
        #pragma unroll
        for (int p = 0; p < 4; ++p) {
            s16x8 af[2][2];
            #pragma unroll
            for (int i = 0; i < 2; ++i)
                #pragma unroll
                for (int ks = 0; ks < 2; ++ks)
                    af[i][ks] = lds_frag(Ah, (2 * p + i) * 16 + lr, ks, lg);
            __builtin_amdgcn_s_setprio(1);
            #pragma unroll
            for (int i = 0; i < 2; ++i)
                #pragma unroll
                for (int nf = 0; nf < 4; ++nf)
                    #pragma unroll
                    for (int ks = 0; ks < 2; ++ks)
                        acc[2 * p + i][nf] = MFMA16(af[i][ks], bf[nf][ks], acc[2 * p + i][nf]);
            __builtin_amdgcn_s_setprio(0);
        }
    }

    int wrow = row0 + wm * 128;
    #pragma unroll
    for (int mf = 0; mf < 8; ++mf) {
        int grow = wrow + mf * 16 + lg * 4;
        #pragma unroll
        for (int nf = 0; nf < 4; ++nf) {
            int gc = col0 + wn * 64 + nf * 16 + lr;
            if (gc >= N) continue;
            if (ROUTE) {
                int which = gc >> 10, lc = gc & 1023;
                float bias = (which == 0 ? bb0 : which == 1 ? bb1 : bb2)[lc];
                float alpha = (which == 0) ? alpha0 : 1.0f;
                short* op = (which == 0 ? o0 : which == 1 ? o1 : o2);
                #pragma unroll
                for (int q = 0; q < 4; ++q) {
                    int r2 = grow + q;
                    if (r2 < M) op[(long)r2 * 1024 + lc] = f2b((acc[mf][nf][q] + bias) * alpha);
                }
            } else {
                float bias = bb0[gc];
                #pragma unroll
                for (int q = 0; q < 4; ++q) {
                    int r2 = grow + q;
                    if (r2 < M) Cf[(long)r2 * N + gc] = acc[mf][nf][q] + bias;
                }
            }
        }
    }
}

// ---------------- 128^2 core for att partials ----------------
__device__ __forceinline__ void gemm_core(
    const short* __restrict__ Ab, const short* __restrict__ Bb,
    float* __restrict__ Cf, int M, int N, int K, int ldc, int row0, int col0) {
    __shared__ short As[128 * 64];
    __shared__ short Bs[128 * 64];
    int tid = threadIdx.x;
    int lane = tid & 63, wave = tid >> 6;
    int wr = wave >> 1, wc = wave & 1;
    int lr = lane & 15, lg = lane >> 4;
    f32x4 acc[4][4];
    #pragma unroll
    for (int i = 0; i < 4; i++)
        #pragma unroll
        for (int j = 0; j < 4; j++)
            #pragma unroll
            for (int q = 0; q < 4; q++) acc[i][j][q] = 0.f;

    for (int k0 = 0; k0 < K; k0 += 64) {
        __syncthreads();
        #pragma unroll
        for (int i = 0; i < 4; ++i) {
            int cw = i * 256 + wave * 64;
            int c = cw + lane;
            int r = c >> 3;
            int cs = (c & 7) * 8;
            int ra = row0 + r; ra = ra < M ? ra : M - 1;
            gload16(Ab + (long)ra * K + k0 + cs, &As[cw * 8]);
            int rb = col0 + r; rb = rb < N ? rb : N - 1;
            gload16(Bb + (long)rb * K + k0 + cs, &Bs[cw * 8]);
        }
        __syncthreads();
        #pragma unroll
        for (int ks = 0; ks < 2; ++ks) {
            s16x8 af[4], bfr[4];
            #pragma unroll
            for (int i = 0; i < 4; ++i)
                af[i] = *(const s16x8*)&As[(wr * 64 + i * 16 + lr) * 64 + ks * 32 + lg * 8];
            #pragma unroll
            for (int j = 0; j < 4; ++j)
                bfr[j] = *(const s16x8*)&Bs[(wc * 64 + j * 16 + lr) * 64 + ks * 32 + lg * 8];
            #pragma unroll
            for (int i = 0; i < 4; ++i)
                #pragma unroll
                for (int j = 0; j < 4; ++j)
                    acc[i][j] = MFMA16(af[i], bfr[j], acc[i][j]);
        }
    }
    #pragma unroll
    for (int i = 0; i < 4; i++) {
        int rbase = row0 + wr * 64 + i * 16 + lg * 4;
        #pragma unroll
        for (int j = 0; j < 4; j++) {
            int c = col0 + wc * 64 + j * 16 + lr;
            if (c >= N) continue;
            #pragma unroll
            for (int q = 0; q < 4; q++) {
                int r = rbase + q;
                if (r >= M) continue;
                Cf[(long)r * ldc + c] = acc[i][j][q];
            }
        }
    }
}

__global__ __launch_bounds__(256) void k_att(
    const short* __restrict__ q, const short* __restrict__ k,
    float* __restrict__ attp, int T, int E) {
    int z = blockIdx.z;
    gemm_core(q + (long)z * T * E, k + (long)z * T * E,
              attp + (long)z * T * T, T, T, E, T,
              blockIdx.y * 128, blockIdx.x * 128);
}

// ---------------- mean over heads of K ----------------
__global__ void k_mean_keys8(const short* __restrict__ Kb, float* __restrict__ out, int BT) {
    int i = blockIdx.x * blockDim.x + threadIdx.x;
    if (i >= BT * 8) return;
    int bt = i >> 3, d0 = (i & 7) * 8;
    const short* p = Kb + (long)bt * 1024 + d0;
    float s[8] = {0.f, 0.f, 0.f, 0.f, 0.f, 0.f, 0.f, 0.f};
    #pragma unroll
    for (int h = 0; h < 16; ++h) {
        s16x8 v = *(const s16x8*)(p + h * 64);
        #pragma unroll
        for (int j = 0; j < 8; ++j) s[j] += b2f(v[j]);
    }
    float4 o0 = {s[0] * 0.0625f, s[1] * 0.0625f, s[2] * 0.0625f, s[3] * 0.0625f};
    float4 o1 = {s[4] * 0.0625f, s[5] * 0.0625f, s[6] * 0.0625f, s[7] * 0.0625f};
    *(float4*)(out + (long)bt * 64 + d0) = o0;
    *(float4*)(out + (long)bt * 64 + d0 + 4) = o1;
}

// ---------------- reduce att_score partials over batch ----------------
// scale = ln2/256 compensates the log2e folded into q
__global__ void k_att_reduce(const float* __restrict__ part, float* __restrict__ out,
                             int n, int nb, long stride) {
    int i = blockIdx.x * blockDim.x + threadIdx.x;
    if (i >= n) return;
    float s = 0.f;
    for (int b = 0; b < nb; ++b) s += part[(long)b * stride + i];
    out[i] = s * 0.002707606174062286f;  // ln(2)/256
}

// ---------------- V transpose: v[B,T,H*64] -> vt[B*H][64][TP] ----------------
__global__ __launch_bounds__(256) void k_vtrans(const short* __restrict__ v, short* __restrict__ vt,
                                                int B, int T, int H, int TP) {
    int b = blockIdx.z, h = blockIdx.y, t0 = blockIdx.x * 64;
    __shared__ short Vs[64][68];
    int tid = threadIdx.x;
    for (int c = tid; c < 512; c += 256) {
        int r = c >> 3, m = c & 7;
        s16x8 val = {0,0,0,0,0,0,0,0};
        if (t0 + r < T) val = *(const s16x8*)(v + ((long)(b * T + t0 + r)) * (H * 64) + h * 64 + m * 8);
        *(s16x8*)&Vs[r][m * 8] = val;
    }
    __syncthreads();
    for (int c = tid; c < 512; c += 256) {
        int d = c >> 3, mw = c & 7;
        s16x8 o;
        #pragma unroll
        for (int j = 0; j < 8; j++) o[j] = Vs[mw * 8 + j][d];
        *(s16x8*)(vt + ((long)((b * H + h) * 64 + d)) * TP + t0 + mw * 8) = o;
    }
}

// ---------------- flash attention v4: size-weighted exp2 softmax, per-lane lsum ----------------
__global__ __launch_bounds__(256) void k_flash(
    const short* __restrict__ Q, const short* __restrict__ Kb, const short* __restrict__ VT,
    const float* __restrict__ szp, short* __restrict__ Ctx,
    int B, int T, int E, int H, int SP, int TP, int NTQ) {
    int nwg = gridDim.x;
    int cpx = nwg >> 3;
    int wg = (blockIdx.x & 7) * cpx + (blockIdx.x >> 3);
    int tq = wg % NTQ, h = (wg / NTQ) % H, b = wg / (NTQ * H);
    int t0 = tq * 128;

    __shared__ short Ks[64][68];
    __shared__ short Vt[64][68];
    __shared__ short Ps[4][32][68];
    __shared__ float Ls[64];
    int tid = threadIdx.x, wid = tid >> 6, lane = tid & 63;
    int lr = lane & 15, lg = lane >> 4;

    // Q fragments directly from global (once per block)
    s16x8 aqf[2][2];
    #pragma unroll
    for (int i = 0; i < 2; ++i) {
        int t = t0 + wid * 32 + i * 16 + lr; t = t < T ? t : T - 1;
        #pragma unroll
        for (int ks = 0; ks < 2; ++ks)
            aqf[i][ks] = *(const s16x8*)(Q + ((long)b * T + t) * E + h * 64 + ks * 32 + lg * 8);
    }

    const short* kb  = Kb + (long)b * T * E + h * 64;
    const short* vtb = VT + ((long)(b * H + h)) * 64 * TP;

    int c0 = tid, c1 = tid + 256;
    int r0 = c0 >> 3, m0 = c0 & 7, r1 = c1 >> 3, m1 = c1 & 7;
    s16x8 kreg0, kreg1, vreg0, vreg1;
    float lreg = 0.f;

    {
        int s = r0; s = s < T ? s : T - 1;
        kreg0 = *(const s16x8*)(kb + (long)s * E + m0 * 8);
        s = r1; s = s < T ? s : T - 1;
        kreg1 = *(const s16x8*)(kb + (long)s * E + m1 * 8);
        vreg0 = *(const s16x8*)(vtb + (long)r0 * TP + 0 + m0 * 8);
        vreg1 = *(const s16x8*)(vtb + (long)r1 * TP + 0 + m1 * 8);
        if (tid < 64) lreg = szp[b * SP + 0 + tid];
    }

    float mreg[2][4], lsum[2][4];
    f32x4 o[2][4];
    #pragma unroll
    for (int i = 0; i < 2; i++)
        #pragma unroll
        for (int q = 0; q < 4; q++) { mreg[i][q] = -INFINITY; lsum[i][q] = 0.f; }
    #pragma unroll
    for (int i = 0; i < 2; i++)
        #pragma unroll
        for (int jd = 0; jd < 4; jd++)
            #pragma unroll
            for (int q = 0; q < 4; q++) o[i][jd][q] = 0.f;

    for (int s0 = 0; s0 < T; s0 += 64) {
        *(s16x8*)&Ks[r0][m0 * 8] = kreg0;
        *(s16x8*)&Ks[r1][m1 * 8] = kreg1;
        *(s16x8*)&Vt[r0][m0 * 8] = vreg0;
        *(s16x8*)&Vt[r1][m1 * 8] = vreg1;
        if (tid < 64) Ls[tid] = lreg;
        __syncthreads();

        if (s0 + 64 < T) {
            int sn = s0 + 64;
            int s = sn + r0; s = s < T ? s : T - 1;
            kreg0 = *(const s16x8*)(kb + (long)s * E + m0 * 8);
            s = sn + r1; s = s < T ? s : T - 1;
            kreg1 = *(const s16x8*)(kb + (long)s * E + m1 * 8);
            vreg0 = *(const s16x8*)(vtb + (long)r0 * TP + sn + m0 * 8);
            vreg1 = *(const s16x8*)(vtb + (long)r1 * TP + sn + m1 * 8);
            if (tid < 64) lreg = szp[b * SP + sn + tid];
        }

        float szv[4];
        #pragma unroll
        for (int j = 0; j < 4; j++) szv[j] = Ls[j * 16 + lr];

        s16x8 kf[2][4];
        #pragma unroll
        for (int ks = 0; ks < 2; ++ks)
            #pragma unroll
            for (int j = 0; j < 4; ++j)
                kf[ks][j] = *(const s16x8*)&Ks[j * 16 + lr][ks * 32 + lg * 8];

        #pragma unroll
        for (int i = 0; i < 2; ++i) {
            f32x4 sf[4];
            #pragma unroll
            for (int j = 0; j < 4; j++)
                #pragma unroll
                for (int q = 0; q < 4; q++) sf[j][q] = 0.f;
            __builtin_amdgcn_s_setprio(1);
            #pragma unroll
            for (int ks = 0; ks < 2; ++ks)
                #pragma unroll
                for (int j = 0; j < 4; j++) sf[j] = MFMA16(aqf[i][ks], kf[ks][j], sf[j]);
            __builtin_amdgcn_s_setprio(0);

            // raw-logit max (size bias < 1 in log2, absorbed by defer threshold)
            float tmax[4];
            #pragma unroll
            for (int q = 0; q < 4; q++)
                tmax[q] = fmaxf(fmaxf(sf[0][q], sf[1][q]), fmaxf(sf[2][q], sf[3][q]));
            int ok = 1;
            #pragma unroll
            for (int q = 0; q < 4; q++) ok &= (tmax[q] <= mreg[i][q] + 11.0f) ? 1 : 0;
            if (!__all(ok)) {
                #pragma unroll
                for (int q = 0; q < 4; q++) {
                    #pragma unroll
                    for (int msk = 1; msk < 16; msk <<= 1)
                        tmax[q] = fmaxf(tmax[q], __shfl_xor(tmax[q], msk));
                    float mn = fmaxf(mreg[i][q], tmax[q]);
                    float al = exp2f(mreg[i][q] - mn);
                    mreg[i][q] = mn;
                    lsum[i][q] *= al;
                    #pragma unroll
                    for (int jd = 0; jd < 4; jd++) o[i][jd][q] *= al;
                }
            }
            // p = exp2(s - m) * size  (padded keys: size 0 -> p 0); per-lane lsum partial
            float rs[4] = {0.f, 0.f, 0.f, 0.f};
            #pragma unroll
            for (int j = 0; j < 4; j++) {
                float szj = szv[j];
                #pragma unroll
                for (int q = 0; q < 4; q++) {
                    float p = exp2f(sf[j][q] - mreg[i][q]) * szj;
                    sf[j][q] = p;
                    rs[q] += p;
                }
            }
            #pragma unroll
            for (int q = 0; q < 4; q++) lsum[i][q] += rs[q];

            #pragma unroll
            for (int j = 0; j < 4; j++)
                #pragma unroll
                for (int q = 0; q < 4; q++)
                    Ps[wid][i * 16 + lg * 4 + q][j * 16 + lr] = f2b(sf[j][q]);

            __builtin_amdgcn_s_setprio(1);
            #pragma unroll
            for (int ks = 0; ks < 2; ++ks) {
                s16x8 ap = *(const s16x8*)&Ps[wid][i * 16 + lr][ks * 32 + lg * 8];
                #pragma unroll
                for (int jd = 0; jd < 4; jd++) {
                    s16x8 bv = *(const s16x8*)&Vt[jd * 16 + lr][ks * 32 + lg * 8];
                    o[i][jd] = MFMA16(ap, bv, o[i][jd]);
                }
            }
            __builtin_amdgcn_s_setprio(0);
        }
        __syncthreads();
    }

    short* cb = Ctx + ((long)b * T + t0) * E + h * 64;
    #pragma unroll
    for (int i = 0; i < 2; i++)
        #pragma unroll
        for (int q = 0; q < 4; q++) {
            float s = lsum[i][q];
            s += __shfl_xor(s, 1); s += __shfl_xor(s, 2);
            s += __shfl_xor(s, 4); s += __shfl_xor(s, 8);
            int t = wid * 32 + i * 16 + lg * 4 + q;
            if (t0 + t >= T) continue;
            float inv = 1.f / s;
            #pragma unroll
            for (int jd = 0; jd < 4; jd++)
                cb[(long)t * E + jd * 16 + lr] = f2b(o[i][jd][q] * inv);
        }
}

extern "C" void kernel_launch(void* const* d_in, const int* in_sizes, int n_in,
                              void* d_out, int out_size, void* d_ws, size_t ws_size,
                              hipStream_t stream) {
    (void)in_sizes; (void)n_in; (void)out_size; (void)ws_size;
    const int B = 16, T = 577, E = 1024, H = 16;
    const int SP = 640, TP = 640;
    const float* hs   = (const float*)d_in[0];
    const float* size = (const float*)d_in[1];
    const float* wq   = (const float*)d_in[2];
    const float* bq   = (const float*)d_in[3];
    const float* wk   = (const float*)d_in[4];
    const float* bk   = (const float*)d_in[5];
    const float* wv   = (const float*)d_in[6];
    const float* bv   = (const float*)d_in[7];
    const float* wo   = (const float*)d_in[8];
    const float* bo   = (const float*)d_in[9];

    float* out_attn = (float*)d_out;                  // B*T*E
    float* out_mk   = out_attn + (long)B * T * E;     // B*T*D
    float* out_as   = out_mk + (long)B * T * 64;      // T*T

    long nBTE = (long)B * T * E;
    long nEE  = (long)E * E;
    char* ws = (char*)d_ws;
    short* hs_b  = (short*)ws; ws += nBTE * 2;
    short* wq_b  = (short*)ws; ws += nEE * 2;   // wq|wk|wv contiguous -> [3072][1024]
    short* wk_b  = (short*)ws; ws += nEE * 2;
    short* wv_b  = (short*)ws; ws += nEE * 2;
    short* wo_b  = (short*)ws; ws += nEE * 2;
    short* q_b   = (short*)ws; ws += nBTE * 2;
    short* k_b   = (short*)ws; ws += nBTE * 2;
    short* v_b   = (short*)ws; ws += nBTE * 2;
    short* ctx_b = (short*)ws; ws += nBTE * 2;
    float* szpad = (float*)ws; ws += (long)B * SP * 4;
    float* att_p = (float*)ws; ws += (long)B * T * T * 4;
    short* vt = (short*)att_p;   // aliases att_p, written after reduce consumed it

    k_f32_to_bf16<<<2048, 256, 0, stream>>>(hs, hs_b, nBTE);
    k_f32_to_bf16<<<1024, 256, 0, stream>>>(wq, wq_b, nEE);
    k_f32_to_bf16<<<1024, 256, 0, stream>>>(wk, wk_b, nEE);
    k_f32_to_bf16<<<1024, 256, 0, stream>>>(wv, wv_b, nEE);
    k_f32_to_bf16<<<1024, 256, 0, stream>>>(wo, wo_b, nEE);
    k_sizepad<<<(B * SP + 255) / 256, 256, 0, stream>>>(size, szpad, B, T, SP);

    int M = B * T;  // 9232
    // fused QKV; q carries 0.125*log2(e) for exp2-domain softmax (compensated in att_reduce)
    {
        int Mtiles = (M + 255) / 256, Ntiles = 3072 / 256;
        k_gemm8<true><<<Mtiles * Ntiles, 512, 0, stream>>>(
            hs_b, wq_b, bq, bk, bv, q_b, k_b, v_b, nullptr, M, 3072, E, Ntiles,
            0.18033688011112042f);  // 0.125 * log2(e)
    }

    dim3 g_att((T + 127) / 128, (T + 127) / 128, B);
    k_att<<<g_att, dim3(256), 0, stream>>>(q_b, k_b, att_p, T, E);
    k_att_reduce<<<((T * T) + 255) / 256, 256, 0, stream>>>(att_p, out_as, T * T, B, (long)T * T);

    dim3 g_vt((T + 63) / 64, H, B);
    k_vtrans<<<g_vt, dim3(256), 0, stream>>>(v_b, vt, B, T, H, TP);

    k_mean_keys8<<<((B * T * 8) + 255) / 256, 256, 0, stream>>>(k_b, out_mk, B * T);

    const int NTQ = (T + 127) / 128;
    int nfl = NTQ * H * B;
    k_flash<<<nfl, dim3(256), 0, stream>>>(q_b, k_b, vt, szpad, ctx_b, B, T, E, H, SP, TP, NTQ);

    {
        int Mtiles = (M + 255) / 256, Ntiles = 1024 / 256;
        k_gemm8<false><<<Mtiles * Ntiles, 512, 0, stream>>>(
            ctx_b, wo_b, bo, nullptr, nullptr, nullptr, nullptr, nullptr,
            out_attn, M, 1024, E, Ntiles, 1.0f);
    }
}